// Round 6
// baseline (702.151 us; speedup 1.0000x reference)
//
#include <hip/hip_runtime.h>

// Problem constants (fixed by the reference file)
#define NN 50000
#define NE 800000
#define NEP (NN + NE)      // edges + self-loops = 850000
#define NG 1024

// ---------------------------------------------------------------------------
// int64-vs-int32 input format probe + normalization.
// The reference declares edge_index/batch as int64; the harness doc says
// integer inputs arrive as int32. Detect at runtime (device-side, graph-safe):
// view buffer as int32; odd positions in the tail window are high-words (==0)
// iff the data is little-endian int64 with values < 2^31.
// ---------------------------------------------------------------------------
__global__ void detect_i64(const int* __restrict__ raw, int n32, int* __restrict__ flag)
{
    __shared__ int nz;
    int tid = threadIdx.x;          // single block of 256
    if (tid == 0) nz = 0;
    __syncthreads();
    int cnt = 0;
    for (int i = tid; i < 1024; i += 256) {
        int p = n32 - 2048 + 2 * i + 1;          // odd int32 positions in tail
        if (p >= 0 && p < n32 && raw[p] != 0) cnt++;
    }
    atomicAdd(&nz, cnt);
    __syncthreads();
    if (tid == 0) flag[0] = (nz == 0) ? 1 : 0;   // 1 -> int64 layout
}

__global__ void cvt_idx(const int* __restrict__ raw, const int* __restrict__ flag,
                        int* __restrict__ out, int n)
{
    int i = blockIdx.x * 256 + threadIdx.x;
    if (i >= n) return;
    out[i] = flag[0] ? raw[2 * i] : raw[i];      // low word if int64
}

// ---------------------------------------------------------------------------
// CSR build: histogram -> exclusive scan -> scatter (dst-indexed)
// ---------------------------------------------------------------------------
__global__ void edge_hist(const int* __restrict__ ei, int* __restrict__ cnt)
{
    int e = blockIdx.x * 256 + threadIdx.x;
    if (e >= NEP) return;
    int dst = (e < NE) ? ei[NE + e] : (e - NE);
    atomicAdd(&cnt[dst], 1);
}

__global__ __launch_bounds__(1024) void scan_counts(const int* __restrict__ cnt,
                                                    int* __restrict__ rowptr, int n)
{
    __shared__ int wsums[16];
    __shared__ int carry_s;
    int tid = threadIdx.x, lane = tid & 63, wid = tid >> 6;
    if (tid == 0) carry_s = 0;
    __syncthreads();
    for (int base = 0; base < n; base += 1024) {
        int i = base + tid;
        int v = (i < n) ? cnt[i] : 0;
        int s = v;
        #pragma unroll
        for (int off = 1; off < 64; off <<= 1) {
            int t = __shfl_up(s, off);
            if (lane >= off) s += t;
        }
        if (lane == 63) wsums[wid] = s;
        __syncthreads();
        if (wid == 0 && lane < 16) {
            int ws = wsums[lane];
            #pragma unroll
            for (int off = 1; off < 16; off <<= 1) {
                int t = __shfl_up(ws, off);
                if (lane >= off) ws += t;
            }
            wsums[lane] = ws;   // inclusive scan of wave sums
        }
        __syncthreads();
        int wave_off = (wid == 0) ? 0 : wsums[wid - 1];
        int carry = carry_s;
        if (i < n) rowptr[i] = carry + wave_off + s - v;   // exclusive
        int total = wsums[15];
        __syncthreads();   // all reads of carry_s/wsums done
        if (tid == 0) carry_s = carry + total;
        __syncthreads();   // carry_s updated before next chunk
    }
    if (tid == 0) rowptr[n] = carry_s;
}

__global__ void copy_int(const int* __restrict__ a, int* __restrict__ b, int n)
{
    int i = blockIdx.x * 256 + threadIdx.x;
    if (i < n) b[i] = a[i];
}

__global__ void edge_scatter(const int* __restrict__ ei, int* __restrict__ cursor,
                             int* __restrict__ csr_src)
{
    int e = blockIdx.x * 256 + threadIdx.x;
    if (e >= NEP) return;
    int src, dst;
    if (e < NE) { src = ei[e]; dst = ei[NE + e]; }
    else        { src = dst = e - NE; }
    int pos = atomicAdd(&cursor[dst], 1);
    csr_src[pos] = src;
}

// ---------------------------------------------------------------------------
// f32 GEMM: C[M,N] = A[M,K] @ B[K,N], row-major. 64x64 tile, 4x4 micro-tile.
// ---------------------------------------------------------------------------
__global__ __launch_bounds__(256) void gemm_f32(const float* __restrict__ A,
                                                const float* __restrict__ B,
                                                float* __restrict__ C,
                                                int M, int N, int K)
{
    const int BM = 64, BN = 64, BK = 32;
    __shared__ float As[BK][BM];
    __shared__ float Bs[BK][BN];
    int tid = threadIdx.x;
    int tx = tid & 15, ty = tid >> 4;
    int row0 = blockIdx.x * BM, col0 = blockIdx.y * BN;
    float acc[4][4] = {};
    for (int k0 = 0; k0 < K; k0 += BK) {
        #pragma unroll
        for (int i = 0; i < 2; i++) {           // A tile: 64x32, transposed store
            int f4 = tid + i * 256;             // 0..511
            int r  = f4 >> 3;                   // 8 float4 per row
            int c4 = (f4 & 7) << 2;
            float4 v = make_float4(0.f, 0.f, 0.f, 0.f);
            int gr = row0 + r;
            if (gr < M) v = *(const float4*)&A[(size_t)gr * K + k0 + c4];
            As[c4 + 0][r] = v.x; As[c4 + 1][r] = v.y;
            As[c4 + 2][r] = v.z; As[c4 + 3][r] = v.w;
        }
        #pragma unroll
        for (int i = 0; i < 2; i++) {           // B tile: 32x64, direct
            int f4 = tid + i * 256;
            int r  = f4 >> 4;                   // 16 float4 per row
            int c4 = (f4 & 15) << 2;
            *(float4*)&Bs[r][c4] = *(const float4*)&B[(size_t)(k0 + r) * N + col0 + c4];
        }
        __syncthreads();
        #pragma unroll
        for (int k = 0; k < BK; k++) {
            float4 a = *(const float4*)&As[k][ty * 4];
            float4 b = *(const float4*)&Bs[k][tx * 4];
            float av[4] = {a.x, a.y, a.z, a.w};
            float bv[4] = {b.x, b.y, b.z, b.w};
            #pragma unroll
            for (int i = 0; i < 4; i++)
                #pragma unroll
                for (int j = 0; j < 4; j++)
                    acc[i][j] += av[i] * bv[j];
        }
        __syncthreads();
    }
    #pragma unroll
    for (int i = 0; i < 4; i++) {
        int gr = row0 + ty * 4 + i;
        if (gr < M) {
            float4 v = make_float4(acc[i][0], acc[i][1], acc[i][2], acc[i][3]);
            *(float4*)&C[(size_t)gr * N + col0 + tx * 4] = v;
        }
    }
}

// ---------------------------------------------------------------------------
// Per-node attention coefficients: asrc[n,h] = dot(h[n,h,:], att_src[h,:])
// One wave per node. 256 threads = 4 nodes/block. float4 loads (G13).
// ---------------------------------------------------------------------------
template <int HEADS>
__global__ __launch_bounds__(256) void compute_alphas(const float* __restrict__ h,
                                                      const float* __restrict__ att_src,
                                                      const float* __restrict__ att_dst,
                                                      float* __restrict__ asrc,
                                                      float* __restrict__ adst, int n)
{
    const int CH  = HEADS * 128;
    const int PER = CH / 64;     // 4 (HEADS=2) or 2 (HEADS=1)
    const int RED = 128 / PER;   // lanes per head: 32 or 64
    int wid = threadIdx.x >> 6, lane = threadIdx.x & 63;
    int node = blockIdx.x * 4 + wid;
    if (node >= n) return;
    float ss = 0.f, sd = 0.f;
    if (PER == 4) {
        float4 hv = *(const float4*)&h[(size_t)node * CH + lane * 4];
        float4 vs = *(const float4*)&att_src[lane * 4];
        float4 vd = *(const float4*)&att_dst[lane * 4];
        ss = hv.x * vs.x + hv.y * vs.y + hv.z * vs.z + hv.w * vs.w;
        sd = hv.x * vd.x + hv.y * vd.y + hv.z * vd.z + hv.w * vd.w;
    } else {
        float2 hv = *(const float2*)&h[(size_t)node * CH + lane * 2];
        float2 vs = *(const float2*)&att_src[lane * 2];
        float2 vd = *(const float2*)&att_dst[lane * 2];
        ss = hv.x * vs.x + hv.y * vs.y;
        sd = hv.x * vd.x + hv.y * vd.y;
    }
    #pragma unroll
    for (int off = RED >> 1; off > 0; off >>= 1) {
        ss += __shfl_xor(ss, off);
        sd += __shfl_xor(sd, off);
    }
    if ((lane & (RED - 1)) == 0) {
        int head = lane / RED;
        asrc[node * HEADS + head] = ss;
        adst[node * HEADS + head] = sd;
    }
}

// ---------------------------------------------------------------------------
// GAT aggregation: per dst node -> softmax over in-edges -> weighted gather sum
// One wave per node, 4 waves/block. out = relu(agg + bias).
// ---------------------------------------------------------------------------
template <int HEADS>
__global__ __launch_bounds__(256) void gat_aggregate(const float* __restrict__ h,
                                                     const float* __restrict__ asrc,
                                                     const float* __restrict__ adst,
                                                     const int* __restrict__ rowptr,
                                                     const int* __restrict__ csr_src,
                                                     const float* __restrict__ bias,
                                                     float* __restrict__ out, int n)
{
    const int CH   = HEADS * 128;
    const int PER  = CH / 64;          // floats per lane
    const int MAXE = 128;              // LDS-cached edge budget per node
    __shared__ float w_lds[4][MAXE * HEADS];
    __shared__ int   s_lds[4][MAXE];
    int wid = threadIdx.x >> 6, lane = threadIdx.x & 63;
    int node = blockIdx.x * 4 + wid;
    if (node >= n) return;

    int start = rowptr[node], end = rowptr[node + 1];
    int deg = end - start;
    bool fast = (deg <= MAXE);
    int head = (PER == 4) ? (lane >> 5) : 0;

    float ad[HEADS], m[HEADS], dsum[HEADS];
    #pragma unroll
    for (int hh = 0; hh < HEADS; hh++) { ad[hh] = adst[node * HEADS + hh]; m[hh] = -1e30f; dsum[hh] = 0.f; }

    // pass 1: e = leaky_relu(asrc[src]+adst[dst]); cache in LDS; wave max
    for (int base = 0; base < deg; base += 64) {
        int j = base + lane;
        if (j < deg) {
            int s = csr_src[start + j];
            if (fast) s_lds[wid][j] = s;
            #pragma unroll
            for (int hh = 0; hh < HEADS; hh++) {
                float v = asrc[s * HEADS + hh] + ad[hh];
                v = (v > 0.f) ? v : 0.2f * v;
                if (fast) w_lds[wid][j * HEADS + hh] = v;
                m[hh] = fmaxf(m[hh], v);
            }
        }
    }
    #pragma unroll
    for (int hh = 0; hh < HEADS; hh++)
        #pragma unroll
        for (int off = 32; off > 0; off >>= 1)
            m[hh] = fmaxf(m[hh], __shfl_xor(m[hh], off));

    // pass 2: exp(e - m), cache, wave sum
    for (int base = 0; base < deg; base += 64) {
        int j = base + lane;
        if (j < deg) {
            #pragma unroll
            for (int hh = 0; hh < HEADS; hh++) {
                float v;
                if (fast) v = w_lds[wid][j * HEADS + hh];
                else {
                    int s = csr_src[start + j];
                    v = asrc[s * HEADS + hh] + ad[hh];
                    v = (v > 0.f) ? v : 0.2f * v;
                }
                float ex = __expf(v - m[hh]);
                if (fast) w_lds[wid][j * HEADS + hh] = ex;
                dsum[hh] += ex;
            }
        }
    }
    #pragma unroll
    for (int hh = 0; hh < HEADS; hh++)
        #pragma unroll
        for (int off = 32; off > 0; off >>= 1)
            dsum[hh] += __shfl_xor(dsum[hh], off);

    float m_l    = (HEADS == 2 && head) ? m[HEADS - 1] : m[0];
    float ad_l   = (HEADS == 2 && head) ? ad[HEADS - 1] : ad[0];
    float inv_l  = 1.0f / ((HEADS == 2 && head) ? dsum[HEADS - 1] : dsum[0]);

    // pass 3: weighted gather-accumulate, 2-deep software pipeline
    float acc[PER];
    #pragma unroll
    for (int p = 0; p < PER; p++) acc[p] = 0.f;

    auto edge_sw = [&](int j, int& s, float& wgt) {
        if (fast) {
            s   = s_lds[wid][j];
            wgt = w_lds[wid][j * HEADS + head] * inv_l;
        } else {
            s = csr_src[start + j];
            float v = asrc[s * HEADS + head] + ad_l;
            v = (v > 0.f) ? v : 0.2f * v;
            wgt = __expf(v - m_l) * inv_l;
        }
    };

    int j = 0;
    int s0 = 0; float w0 = 0.f;
    if (deg > 0) edge_sw(0, s0, w0);
    for (; j + 1 < deg; j++) {
        int s1; float w1;
        edge_sw(j + 1, s1, w1);              // prefetch next edge's metadata
        if (PER == 4) {
            float4 hv = *(const float4*)&h[(size_t)s0 * CH + lane * 4];
            acc[0] += w0 * hv.x; acc[1] += w0 * hv.y;
            acc[2] += w0 * hv.z; acc[3] += w0 * hv.w;
        } else {
            float2 hv = *(const float2*)&h[(size_t)s0 * CH + lane * 2];
            acc[0] += w0 * hv.x; acc[1] += w0 * hv.y;
        }
        s0 = s1; w0 = w1;
    }
    if (deg > 0) {
        if (PER == 4) {
            float4 hv = *(const float4*)&h[(size_t)s0 * CH + lane * 4];
            acc[0] += w0 * hv.x; acc[1] += w0 * hv.y;
            acc[2] += w0 * hv.z; acc[3] += w0 * hv.w;
        } else {
            float2 hv = *(const float2*)&h[(size_t)s0 * CH + lane * 2];
            acc[0] += w0 * hv.x; acc[1] += w0 * hv.y;
        }
    }

    #pragma unroll
    for (int p = 0; p < PER; p++) {
        float v = acc[p] + bias[lane * PER + p];
        out[(size_t)node * CH + lane * PER + p] = fmaxf(v, 0.f);
    }
}

// ---------------------------------------------------------------------------
// Global mean pool (atomic) + tiny MLP head
// ---------------------------------------------------------------------------
__global__ void pool_kernel(const float* __restrict__ h, const int* __restrict__ batch,
                            float* __restrict__ pool, int* __restrict__ cnt)
{
    int t = blockIdx.x * 256 + threadIdx.x;
    int node = t >> 5, sub = t & 31;
    if (node >= NN) return;
    int g = batch[node];
    float4 v = *(const float4*)&h[(size_t)node * 128 + sub * 4];
    atomicAdd(&pool[g * 128 + sub * 4 + 0], v.x);
    atomicAdd(&pool[g * 128 + sub * 4 + 1], v.y);
    atomicAdd(&pool[g * 128 + sub * 4 + 2], v.z);
    atomicAdd(&pool[g * 128 + sub * 4 + 3], v.w);
    if (sub == 0) atomicAdd(&cnt[g], 1);
}

__global__ __launch_bounds__(64) void head_mlp(const float* __restrict__ pool,
                                               const int* __restrict__ cnt,
                                               const float* __restrict__ lw1,
                                               const float* __restrict__ lb1,
                                               const float* __restrict__ lw2,
                                               const float* __restrict__ lb2,
                                               float* __restrict__ out)
{
    int g = blockIdx.x, lane = threadIdx.x;
    __shared__ float p[128];
    float c = fmaxf((float)cnt[g], 1.0f);
    float invc = 1.0f / c;
    p[lane]      = pool[g * 128 + lane] * invc;
    p[lane + 64] = pool[g * 128 + lane + 64] * invc;
    __syncthreads();
    float z = lb1[lane];
    #pragma unroll 8
    for (int k = 0; k < 128; k++) z += p[k] * lw1[k * 64 + lane];
    z = fmaxf(z, 0.f);
    float v = z * lw2[lane];
    #pragma unroll
    for (int off = 32; off > 0; off >>= 1) v += __shfl_xor(v, off);
    if (lane == 0) out[g] = v + lb2[0];
}

// ---------------------------------------------------------------------------
extern "C" void kernel_launch(void* const* d_in, const int* in_sizes, int n_in,
                              void* d_out, int out_size, void* d_ws, size_t ws_size,
                              hipStream_t stream)
{
    const float* x      = (const float*)d_in[0];
    const int*   ei_raw = (const int*)d_in[1];
    const int*   bat_raw= (const int*)d_in[2];
    const float* W1   = (const float*)d_in[4];
    const float* as1  = (const float*)d_in[5];
    const float* ad1  = (const float*)d_in[6];
    const float* b1   = (const float*)d_in[7];
    const float* W2   = (const float*)d_in[8];
    const float* as2  = (const float*)d_in[9];
    const float* ad2  = (const float*)d_in[10];
    const float* b2   = (const float*)d_in[11];
    const float* lw1  = (const float*)d_in[12];
    const float* lb1  = (const float*)d_in[13];
    const float* lw2  = (const float*)d_in[14];
    const float* lb2  = (const float*)d_in[15];
    float* out = (float*)d_out;

    char* w = (char*)d_ws;
    auto alloc = [&](size_t bytes) { char* p = w; w += (bytes + 255) & ~size_t(255); return p; };
    float* h1    = (float*)alloc((size_t)NN * 256 * 4);
    float* o1    = (float*)alloc((size_t)NN * 256 * 4);
    float* h2    = (float*)alloc((size_t)NN * 128 * 4);
    float* o2    = (float*)alloc((size_t)NN * 128 * 4);
    float* asrc1 = (float*)alloc((size_t)NN * 2 * 4);
    float* adst1 = (float*)alloc((size_t)NN * 2 * 4);
    float* asrc2 = (float*)alloc((size_t)NN * 4);
    float* adst2 = (float*)alloc((size_t)NN * 4);
    int*   cnts  = (int*)alloc((size_t)NN * 4);
    int*   rowp  = (int*)alloc((size_t)(NN + 4) * 4);
    int*   curs  = (int*)alloc((size_t)NN * 4);
    int*   csr   = (int*)alloc((size_t)NEP * 4);
    float* pool  = (float*)alloc((size_t)NG * 128 * 4);
    int*   gcnt  = (int*)alloc((size_t)NG * 4);
    int*   ei32  = (int*)alloc((size_t)2 * NE * 4);
    int*   bat32 = (int*)alloc((size_t)NN * 4);
    int*   flags = (int*)alloc(2 * 4);

    // normalize integer inputs (int64 or int32 -> int32)
    detect_i64<<<1, 256, 0, stream>>>(ei_raw, 2 * NE, &flags[0]);
    detect_i64<<<1, 256, 0, stream>>>(bat_raw, NN, &flags[1]);
    cvt_idx<<<(2 * NE + 255) / 256, 256, 0, stream>>>(ei_raw, &flags[0], ei32, 2 * NE);
    cvt_idx<<<(NN + 255) / 256, 256, 0, stream>>>(bat_raw, &flags[1], bat32, NN);

    // CSR build (shared by both layers)
    hipMemsetAsync(cnts, 0, NN * 4, stream);
    edge_hist<<<(NEP + 255) / 256, 256, 0, stream>>>(ei32, cnts);
    scan_counts<<<1, 1024, 0, stream>>>(cnts, rowp, NN);
    copy_int<<<(NN + 255) / 256, 256, 0, stream>>>(rowp, curs, NN);
    edge_scatter<<<(NEP + 255) / 256, 256, 0, stream>>>(ei32, curs, csr);

    // layer 1: h1 = x@W1 ; alphas ; aggregate -> o1 = relu(agg + b1)
    gemm_f32<<<dim3((NN + 63) / 64, 4), 256, 0, stream>>>(x, W1, h1, NN, 256, 128);
    compute_alphas<2><<<(NN + 3) / 4, 256, 0, stream>>>(h1, as1, ad1, asrc1, adst1, NN);
    gat_aggregate<2><<<(NN + 3) / 4, 256, 0, stream>>>(h1, asrc1, adst1, rowp, csr, b1, o1, NN);

    // layer 2
    gemm_f32<<<dim3((NN + 63) / 64, 2), 256, 0, stream>>>(o1, W2, h2, NN, 128, 256);
    compute_alphas<1><<<(NN + 3) / 4, 256, 0, stream>>>(h2, as2, ad2, asrc2, adst2, NN);
    gat_aggregate<1><<<(NN + 3) / 4, 256, 0, stream>>>(h2, asrc2, adst2, rowp, csr, b2, o2, NN);

    // pool + head
    hipMemsetAsync(pool, 0, NG * 128 * 4, stream);
    hipMemsetAsync(gcnt, 0, NG * 4, stream);
    pool_kernel<<<(NN * 32 + 255) / 256, 256, 0, stream>>>(o2, bat32, pool, gcnt);
    head_mlp<<<NG, 64, 0, stream>>>(pool, gcnt, lw1, lb1, lw2, lb2, out);
}

// Round 8
// 685.838 us; speedup vs baseline: 1.0238x; 1.0238x over previous
//
#include <hip/hip_runtime.h>

// Problem constants (fixed by the reference file)
#define NN 50000
#define NE 800000
#define NEP (NN + NE)      // edges + self-loops = 850000
#define NG 1024

// ---------------------------------------------------------------------------
// int64-vs-int32 input format probe + normalization.
// ---------------------------------------------------------------------------
__global__ void detect_i64(const int* __restrict__ raw, int n32, int* __restrict__ flag)
{
    __shared__ int nz;
    int tid = threadIdx.x;          // single block of 256
    if (tid == 0) nz = 0;
    __syncthreads();
    int cnt = 0;
    for (int i = tid; i < 1024; i += 256) {
        int p = n32 - 2048 + 2 * i + 1;          // odd int32 positions in tail
        if (p >= 0 && p < n32 && raw[p] != 0) cnt++;
    }
    atomicAdd(&nz, cnt);
    __syncthreads();
    if (tid == 0) flag[0] = (nz == 0) ? 1 : 0;   // 1 -> int64 layout
}

__global__ void cvt_idx(const int* __restrict__ raw, const int* __restrict__ flag,
                        int* __restrict__ out, int n)
{
    int i = blockIdx.x * 256 + threadIdx.x;
    if (i >= n) return;
    out[i] = flag[0] ? raw[2 * i] : raw[i];      // low word if int64
}

// ---------------------------------------------------------------------------
// CSR build: histogram -> exclusive scan -> scatter (dst-indexed)
// ---------------------------------------------------------------------------
__global__ void edge_hist(const int* __restrict__ ei, int* __restrict__ cnt)
{
    int e = blockIdx.x * 256 + threadIdx.x;
    if (e >= NEP) return;
    int dst = (e < NE) ? ei[NE + e] : (e - NE);
    atomicAdd(&cnt[dst], 1);
}

__global__ __launch_bounds__(1024) void scan_counts(const int* __restrict__ cnt,
                                                    int* __restrict__ rowptr, int n)
{
    __shared__ int wsums[16];
    __shared__ int carry_s;
    int tid = threadIdx.x, lane = tid & 63, wid = tid >> 6;
    if (tid == 0) carry_s = 0;
    __syncthreads();
    for (int base = 0; base < n; base += 1024) {
        int i = base + tid;
        int v = (i < n) ? cnt[i] : 0;
        int s = v;
        #pragma unroll
        for (int off = 1; off < 64; off <<= 1) {
            int t = __shfl_up(s, off);
            if (lane >= off) s += t;
        }
        if (lane == 63) wsums[wid] = s;
        __syncthreads();
        if (wid == 0 && lane < 16) {
            int ws = wsums[lane];
            #pragma unroll
            for (int off = 1; off < 16; off <<= 1) {
                int t = __shfl_up(ws, off);
                if (lane >= off) ws += t;
            }
            wsums[lane] = ws;   // inclusive scan of wave sums
        }
        __syncthreads();
        int wave_off = (wid == 0) ? 0 : wsums[wid - 1];
        int carry = carry_s;
        if (i < n) rowptr[i] = carry + wave_off + s - v;   // exclusive
        int total = wsums[15];
        __syncthreads();   // all reads of carry_s/wsums done
        if (tid == 0) carry_s = carry + total;
        __syncthreads();   // carry_s updated before next chunk
    }
    if (tid == 0) rowptr[n] = carry_s;
}

__global__ void copy_int(const int* __restrict__ a, int* __restrict__ b, int n)
{
    int i = blockIdx.x * 256 + threadIdx.x;
    if (i < n) b[i] = a[i];
}

__global__ void edge_scatter(const int* __restrict__ ei, int* __restrict__ cursor,
                             int* __restrict__ csr_src)
{
    int e = blockIdx.x * 256 + threadIdx.x;
    if (e >= NEP) return;
    int src, dst;
    if (e < NE) { src = ei[e]; dst = ei[NE + e]; }
    else        { src = dst = e - NE; }
    int pos = atomicAdd(&cursor[dst], 1);
    csr_src[pos] = src;
}

// ---------------------------------------------------------------------------
// f32 GEMM: C[M,N] = A[M,K] @ B[K,N], row-major. 64x64 tile, 4x4 micro-tile.
// ---------------------------------------------------------------------------
__global__ __launch_bounds__(256) void gemm_f32(const float* __restrict__ A,
                                                const float* __restrict__ B,
                                                float* __restrict__ C,
                                                int M, int N, int K)
{
    const int BM = 64, BN = 64, BK = 32;
    __shared__ float As[BK][BM];
    __shared__ float Bs[BK][BN];
    int tid = threadIdx.x;
    int tx = tid & 15, ty = tid >> 4;
    int row0 = blockIdx.x * BM, col0 = blockIdx.y * BN;
    float acc[4][4] = {};
    for (int k0 = 0; k0 < K; k0 += BK) {
        #pragma unroll
        for (int i = 0; i < 2; i++) {           // A tile: 64x32, transposed store
            int f4 = tid + i * 256;             // 0..511
            int r  = f4 >> 3;                   // 8 float4 per row
            int c4 = (f4 & 7) << 2;
            float4 v = make_float4(0.f, 0.f, 0.f, 0.f);
            int gr = row0 + r;
            if (gr < M) v = *(const float4*)&A[(size_t)gr * K + k0 + c4];
            As[c4 + 0][r] = v.x; As[c4 + 1][r] = v.y;
            As[c4 + 2][r] = v.z; As[c4 + 3][r] = v.w;
        }
        #pragma unroll
        for (int i = 0; i < 2; i++) {           // B tile: 32x64, direct
            int f4 = tid + i * 256;
            int r  = f4 >> 4;                   // 16 float4 per row
            int c4 = (f4 & 15) << 2;
            *(float4*)&Bs[r][c4] = *(const float4*)&B[(size_t)(k0 + r) * N + col0 + c4];
        }
        __syncthreads();
        #pragma unroll
        for (int k = 0; k < BK; k++) {
            float4 a = *(const float4*)&As[k][ty * 4];
            float4 b = *(const float4*)&Bs[k][tx * 4];
            float av[4] = {a.x, a.y, a.z, a.w};
            float bv[4] = {b.x, b.y, b.z, b.w};
            #pragma unroll
            for (int i = 0; i < 4; i++)
                #pragma unroll
                for (int j = 0; j < 4; j++)
                    acc[i][j] += av[i] * bv[j];
        }
        __syncthreads();
    }
    #pragma unroll
    for (int i = 0; i < 4; i++) {
        int gr = row0 + ty * 4 + i;
        if (gr < M) {
            float4 v = make_float4(acc[i][0], acc[i][1], acc[i][2], acc[i][3]);
            *(float4*)&C[(size_t)gr * N + col0 + tx * 4] = v;
        }
    }
}

// ---------------------------------------------------------------------------
// Per-node attention coefficients: asrc[n,h] = dot(h[n,h,:], att_src[h,:])
// ---------------------------------------------------------------------------
template <int HEADS>
__global__ __launch_bounds__(256) void compute_alphas(const float* __restrict__ h,
                                                      const float* __restrict__ att_src,
                                                      const float* __restrict__ att_dst,
                                                      float* __restrict__ asrc,
                                                      float* __restrict__ adst, int n)
{
    const int CH  = HEADS * 128;
    const int PER = CH / 64;     // 4 (HEADS=2) or 2 (HEADS=1)
    const int RED = 128 / PER;   // lanes per head: 32 or 64
    int wid = threadIdx.x >> 6, lane = threadIdx.x & 63;
    int node = blockIdx.x * 4 + wid;
    if (node >= n) return;
    float ss = 0.f, sd = 0.f;
    if (PER == 4) {
        float4 hv = *(const float4*)&h[(size_t)node * CH + lane * 4];
        float4 vs = *(const float4*)&att_src[lane * 4];
        float4 vd = *(const float4*)&att_dst[lane * 4];
        ss = hv.x * vs.x + hv.y * vs.y + hv.z * vs.z + hv.w * vs.w;
        sd = hv.x * vd.x + hv.y * vd.y + hv.z * vd.z + hv.w * vd.w;
    } else {
        float2 hv = *(const float2*)&h[(size_t)node * CH + lane * 2];
        float2 vs = *(const float2*)&att_src[lane * 2];
        float2 vd = *(const float2*)&att_dst[lane * 2];
        ss = hv.x * vs.x + hv.y * vs.y;
        sd = hv.x * vd.x + hv.y * vd.y;
    }
    #pragma unroll
    for (int off = RED >> 1; off > 0; off >>= 1) {
        ss += __shfl_xor(ss, off);
        sd += __shfl_xor(sd, off);
    }
    if ((lane & (RED - 1)) == 0) {
        int head = lane / RED;
        asrc[node * HEADS + head] = ss;
        adst[node * HEADS + head] = sd;
    }
}

// ---------------------------------------------------------------------------
// GAT aggregation: per dst node -> softmax over in-edges -> weighted gather sum
// Pass 3 gather is 8-deep unrolled: 8 independent h-row loads in flight/wave
// (round-6 counters: 1-deep was latency-limited at 3.76 TB/s, 47% peak).
// ---------------------------------------------------------------------------
template <int HEADS>
__global__ __launch_bounds__(256) void gat_aggregate(const float* __restrict__ h,
                                                     const float* __restrict__ asrc,
                                                     const float* __restrict__ adst,
                                                     const int* __restrict__ rowptr,
                                                     const int* __restrict__ csr_src,
                                                     const float* __restrict__ bias,
                                                     float* __restrict__ out, int n)
{
    const int CH   = HEADS * 128;
    const int PER  = CH / 64;          // floats per lane
    const int MAXE = 128;              // LDS-cached edge budget per node
    __shared__ float w_lds[4][MAXE * HEADS];
    __shared__ int   s_lds[4][MAXE];
    int wid = threadIdx.x >> 6, lane = threadIdx.x & 63;
    int node = blockIdx.x * 4 + wid;
    if (node >= n) return;

    int start = rowptr[node], end = rowptr[node + 1];
    int deg = end - start;
    bool fast = (deg <= MAXE);
    int head = (PER == 4) ? (lane >> 5) : 0;

    float ad[HEADS], m[HEADS], dsum[HEADS];
    #pragma unroll
    for (int hh = 0; hh < HEADS; hh++) { ad[hh] = adst[node * HEADS + hh]; m[hh] = -1e30f; dsum[hh] = 0.f; }

    // pass 1: e = leaky_relu(asrc[src]+adst[dst]); cache in LDS; wave max
    for (int base = 0; base < deg; base += 64) {
        int j = base + lane;
        if (j < deg) {
            int s = csr_src[start + j];
            if (fast) s_lds[wid][j] = s;
            #pragma unroll
            for (int hh = 0; hh < HEADS; hh++) {
                float v = asrc[s * HEADS + hh] + ad[hh];
                v = (v > 0.f) ? v : 0.2f * v;
                if (fast) w_lds[wid][j * HEADS + hh] = v;
                m[hh] = fmaxf(m[hh], v);
            }
        }
    }
    #pragma unroll
    for (int hh = 0; hh < HEADS; hh++)
        #pragma unroll
        for (int off = 32; off > 0; off >>= 1)
            m[hh] = fmaxf(m[hh], __shfl_xor(m[hh], off));

    // pass 2: exp(e - m), cache, wave sum
    for (int base = 0; base < deg; base += 64) {
        int j = base + lane;
        if (j < deg) {
            #pragma unroll
            for (int hh = 0; hh < HEADS; hh++) {
                float v;
                if (fast) v = w_lds[wid][j * HEADS + hh];
                else {
                    int s = csr_src[start + j];
                    v = asrc[s * HEADS + hh] + ad[hh];
                    v = (v > 0.f) ? v : 0.2f * v;
                }
                float ex = __expf(v - m[hh]);
                if (fast) w_lds[wid][j * HEADS + hh] = ex;
                dsum[hh] += ex;
            }
        }
    }
    #pragma unroll
    for (int hh = 0; hh < HEADS; hh++)
        #pragma unroll
        for (int off = 32; off > 0; off >>= 1)
            dsum[hh] += __shfl_xor(dsum[hh], off);

    float m_l    = (HEADS == 2 && head) ? m[HEADS - 1] : m[0];
    float ad_l   = (HEADS == 2 && head) ? ad[HEADS - 1] : ad[0];
    float inv_l  = 1.0f / ((HEADS == 2 && head) ? dsum[HEADS - 1] : dsum[0]);

    // pass 3: weighted gather-accumulate, 8-deep unroll for MLP
    float acc[PER];
    #pragma unroll
    for (int p = 0; p < PER; p++) acc[p] = 0.f;

    auto edge_sw = [&](int j, int& s, float& wgt) {
        if (fast) {
            s   = s_lds[wid][j];
            wgt = w_lds[wid][j * HEADS + head] * inv_l;
        } else {
            s = csr_src[start + j];
            float v = asrc[s * HEADS + head] + ad_l;
            v = (v > 0.f) ? v : 0.2f * v;
            wgt = __expf(v - m_l) * inv_l;
        }
    };

    const int U = 8;
    int j = 0;
    for (; j + U <= deg; j += U) {
        int su[U]; float wu[U];
        #pragma unroll
        for (int u = 0; u < U; u++) edge_sw(j + u, su[u], wu[u]);
        if (PER == 4) {
            float4 hv[U];
            #pragma unroll
            for (int u = 0; u < U; u++)       // 8 independent 16B loads in flight
                hv[u] = *(const float4*)&h[(size_t)su[u] * CH + lane * 4];
            #pragma unroll
            for (int u = 0; u < U; u++) {
                acc[0] += wu[u] * hv[u].x; acc[1] += wu[u] * hv[u].y;
                acc[2] += wu[u] * hv[u].z; acc[3] += wu[u] * hv[u].w;
            }
        } else {
            float2 hv[U];
            #pragma unroll
            for (int u = 0; u < U; u++)
                hv[u] = *(const float2*)&h[(size_t)su[u] * CH + lane * 2];
            #pragma unroll
            for (int u = 0; u < U; u++) {
                acc[0] += wu[u] * hv[u].x; acc[1] += wu[u] * hv[u].y;
            }
        }
    }
    for (; j < deg; j++) {
        int s; float wgt;
        edge_sw(j, s, wgt);
        if (PER == 4) {
            float4 hv = *(const float4*)&h[(size_t)s * CH + lane * 4];
            acc[0] += wgt * hv.x; acc[1] += wgt * hv.y;
            acc[2] += wgt * hv.z; acc[3] += wgt * hv.w;
        } else {
            float2 hv = *(const float2*)&h[(size_t)s * CH + lane * 2];
            acc[0] += wgt * hv.x; acc[1] += wgt * hv.y;
        }
    }

    #pragma unroll
    for (int p = 0; p < PER; p++) {
        float v = acc[p] + bias[lane * PER + p];
        out[(size_t)node * CH + lane * PER + p] = fmaxf(v, 0.f);
    }
}

// ---------------------------------------------------------------------------
// Global mean pool (atomic) + tiny MLP head
// ---------------------------------------------------------------------------
__global__ void pool_kernel(const float* __restrict__ h, const int* __restrict__ batch,
                            float* __restrict__ pool, int* __restrict__ cnt)
{
    int t = blockIdx.x * 256 + threadIdx.x;
    int node = t >> 5, sub = t & 31;
    if (node >= NN) return;
    int g = batch[node];
    float4 v = *(const float4*)&h[(size_t)node * 128 + sub * 4];
    atomicAdd(&pool[g * 128 + sub * 4 + 0], v.x);
    atomicAdd(&pool[g * 128 + sub * 4 + 1], v.y);
    atomicAdd(&pool[g * 128 + sub * 4 + 2], v.z);
    atomicAdd(&pool[g * 128 + sub * 4 + 3], v.w);
    if (sub == 0) atomicAdd(&cnt[g], 1);
}

__global__ __launch_bounds__(64) void head_mlp(const float* __restrict__ pool,
                                               const int* __restrict__ cnt,
                                               const float* __restrict__ lw1,
                                               const float* __restrict__ lb1,
                                               const float* __restrict__ lw2,
                                               const float* __restrict__ lb2,
                                               float* __restrict__ out)
{
    int g = blockIdx.x, lane = threadIdx.x;
    __shared__ float p[128];
    float c = fmaxf((float)cnt[g], 1.0f);
    float invc = 1.0f / c;
    p[lane]      = pool[g * 128 + lane] * invc;
    p[lane + 64] = pool[g * 128 + lane + 64] * invc;
    __syncthreads();
    float z = lb1[lane];
    #pragma unroll 8
    for (int k = 0; k < 128; k++) z += p[k] * lw1[k * 64 + lane];
    z = fmaxf(z, 0.f);
    float v = z * lw2[lane];
    #pragma unroll
    for (int off = 32; off > 0; off >>= 1) v += __shfl_xor(v, off);
    if (lane == 0) out[g] = v + lb2[0];
}

// ---------------------------------------------------------------------------
extern "C" void kernel_launch(void* const* d_in, const int* in_sizes, int n_in,
                              void* d_out, int out_size, void* d_ws, size_t ws_size,
                              hipStream_t stream)
{
    const float* x      = (const float*)d_in[0];
    const int*   ei_raw = (const int*)d_in[1];
    const int*   bat_raw= (const int*)d_in[2];
    const float* W1   = (const float*)d_in[4];
    const float* as1  = (const float*)d_in[5];
    const float* ad1  = (const float*)d_in[6];
    const float* b1   = (const float*)d_in[7];
    const float* W2   = (const float*)d_in[8];
    const float* as2  = (const float*)d_in[9];
    const float* ad2  = (const float*)d_in[10];
    const float* b2   = (const float*)d_in[11];
    const float* lw1  = (const float*)d_in[12];
    const float* lb1  = (const float*)d_in[13];
    const float* lw2  = (const float*)d_in[14];
    const float* lb2  = (const float*)d_in[15];
    float* out = (float*)d_out;

    char* w = (char*)d_ws;
    auto alloc = [&](size_t bytes) { char* p = w; w += (bytes + 255) & ~size_t(255); return p; };
    float* h1    = (float*)alloc((size_t)NN * 256 * 4);
    float* o1    = (float*)alloc((size_t)NN * 256 * 4);
    float* h2    = (float*)alloc((size_t)NN * 128 * 4);
    float* o2    = (float*)alloc((size_t)NN * 128 * 4);
    float* asrc1 = (float*)alloc((size_t)NN * 2 * 4);
    float* adst1 = (float*)alloc((size_t)NN * 2 * 4);
    float* asrc2 = (float*)alloc((size_t)NN * 4);
    float* adst2 = (float*)alloc((size_t)NN * 4);
    int*   cnts  = (int*)alloc((size_t)NN * 4);
    int*   rowp  = (int*)alloc((size_t)(NN + 4) * 4);
    int*   curs  = (int*)alloc((size_t)NN * 4);
    int*   csr   = (int*)alloc((size_t)NEP * 4);
    float* pool  = (float*)alloc((size_t)NG * 128 * 4);
    int*   gcnt  = (int*)alloc((size_t)NG * 4);
    int*   ei32  = (int*)alloc((size_t)2 * NE * 4);
    int*   bat32 = (int*)alloc((size_t)NN * 4);
    int*   flags = (int*)alloc(2 * 4);

    // normalize integer inputs (int64 or int32 -> int32)
    detect_i64<<<1, 256, 0, stream>>>(ei_raw, 2 * NE, &flags[0]);
    detect_i64<<<1, 256, 0, stream>>>(bat_raw, NN, &flags[1]);
    cvt_idx<<<(2 * NE + 255) / 256, 256, 0, stream>>>(ei_raw, &flags[0], ei32, 2 * NE);
    cvt_idx<<<(NN + 255) / 256, 256, 0, stream>>>(bat_raw, &flags[1], bat32, NN);

    // CSR build (shared by both layers)
    hipMemsetAsync(cnts, 0, NN * 4, stream);
    edge_hist<<<(NEP + 255) / 256, 256, 0, stream>>>(ei32, cnts);
    scan_counts<<<1, 1024, 0, stream>>>(cnts, rowp, NN);
    copy_int<<<(NN + 255) / 256, 256, 0, stream>>>(rowp, curs, NN);
    edge_scatter<<<(NEP + 255) / 256, 256, 0, stream>>>(ei32, curs, csr);

    // layer 1: h1 = x@W1 ; alphas ; aggregate -> o1 = relu(agg + b1)
    gemm_f32<<<dim3((NN + 63) / 64, 4), 256, 0, stream>>>(x, W1, h1, NN, 256, 128);
    compute_alphas<2><<<(NN + 3) / 4, 256, 0, stream>>>(h1, as1, ad1, asrc1, adst1, NN);
    gat_aggregate<2><<<(NN + 3) / 4, 256, 0, stream>>>(h1, asrc1, adst1, rowp, csr, b1, o1, NN);

    // layer 2
    gemm_f32<<<dim3((NN + 63) / 64, 2), 256, 0, stream>>>(o1, W2, h2, NN, 128, 256);
    compute_alphas<1><<<(NN + 3) / 4, 256, 0, stream>>>(h2, as2, ad2, asrc2, adst2, NN);
    gat_aggregate<1><<<(NN + 3) / 4, 256, 0, stream>>>(h2, asrc2, adst2, rowp, csr, b2, o2, NN);

    // pool + head
    hipMemsetAsync(pool, 0, NG * 128 * 4, stream);
    hipMemsetAsync(gcnt, 0, NG * 4, stream);
    pool_kernel<<<(NN * 32 + 255) / 256, 256, 0, stream>>>(o2, bat32, pool, gcnt);
    head_mlp<<<NG, 64, 0, stream>>>(pool, gcnt, lw1, lb1, lw2, lb2, out);
}

// Round 9
// 509.586 us; speedup vs baseline: 1.3779x; 1.3459x over previous
//
#include <hip/hip_runtime.h>

// Problem constants (fixed by the reference file)
#define NN 50000
#define NE 800000
#define NEP (NN + NE)      // edges + self-loops = 850000
#define NG 1024

// bf16 helpers (internal approximation only; reference is all-f32)
__device__ inline unsigned short f2b(float f) {
    unsigned int u = __float_as_uint(f);
    unsigned int r = (u + 0x7FFFu + ((u >> 16) & 1u)) >> 16;   // round-nearest-even
    return (unsigned short)r;
}
__device__ inline float b2f(unsigned short b) {
    return __uint_as_float(((unsigned int)b) << 16);
}

// ---------------------------------------------------------------------------
// int64-vs-int32 input format probe + normalization.
// ---------------------------------------------------------------------------
__global__ void detect_i64(const int* __restrict__ raw, int n32, int* __restrict__ flag)
{
    __shared__ int nz;
    int tid = threadIdx.x;          // single block of 256
    if (tid == 0) nz = 0;
    __syncthreads();
    int cnt = 0;
    for (int i = tid; i < 1024; i += 256) {
        int p = n32 - 2048 + 2 * i + 1;          // odd int32 positions in tail
        if (p >= 0 && p < n32 && raw[p] != 0) cnt++;
    }
    atomicAdd(&nz, cnt);
    __syncthreads();
    if (tid == 0) flag[0] = (nz == 0) ? 1 : 0;   // 1 -> int64 layout
}

__global__ void cvt_idx(const int* __restrict__ raw, const int* __restrict__ flag,
                        int* __restrict__ out, int n)
{
    int i = blockIdx.x * 256 + threadIdx.x;
    if (i >= n) return;
    out[i] = flag[0] ? raw[2 * i] : raw[i];      // low word if int64
}

// ---------------------------------------------------------------------------
// CSR build: histogram -> exclusive scan -> scatter (dst-indexed)
// ---------------------------------------------------------------------------
__global__ void edge_hist(const int* __restrict__ ei, int* __restrict__ cnt)
{
    int e = blockIdx.x * 256 + threadIdx.x;
    if (e >= NEP) return;
    int dst = (e < NE) ? ei[NE + e] : (e - NE);
    atomicAdd(&cnt[dst], 1);
}

__global__ __launch_bounds__(1024) void scan_counts(const int* __restrict__ cnt,
                                                    int* __restrict__ rowptr, int n)
{
    __shared__ int wsums[16];
    __shared__ int carry_s;
    int tid = threadIdx.x, lane = tid & 63, wid = tid >> 6;
    if (tid == 0) carry_s = 0;
    __syncthreads();
    for (int base = 0; base < n; base += 1024) {
        int i = base + tid;
        int v = (i < n) ? cnt[i] : 0;
        int s = v;
        #pragma unroll
        for (int off = 1; off < 64; off <<= 1) {
            int t = __shfl_up(s, off);
            if (lane >= off) s += t;
        }
        if (lane == 63) wsums[wid] = s;
        __syncthreads();
        if (wid == 0 && lane < 16) {
            int ws = wsums[lane];
            #pragma unroll
            for (int off = 1; off < 16; off <<= 1) {
                int t = __shfl_up(ws, off);
                if (lane >= off) ws += t;
            }
            wsums[lane] = ws;   // inclusive scan of wave sums
        }
        __syncthreads();
        int wave_off = (wid == 0) ? 0 : wsums[wid - 1];
        int carry = carry_s;
        if (i < n) rowptr[i] = carry + wave_off + s - v;   // exclusive
        int total = wsums[15];
        __syncthreads();   // all reads of carry_s/wsums done
        if (tid == 0) carry_s = carry + total;
        __syncthreads();   // carry_s updated before next chunk
    }
    if (tid == 0) rowptr[n] = carry_s;
}

__global__ void copy_int(const int* __restrict__ a, int* __restrict__ b, int n)
{
    int i = blockIdx.x * 256 + threadIdx.x;
    if (i < n) b[i] = a[i];
}

__global__ void edge_scatter(const int* __restrict__ ei, int* __restrict__ cursor,
                             int* __restrict__ csr_src)
{
    int e = blockIdx.x * 256 + threadIdx.x;
    if (e >= NEP) return;
    int src, dst;
    if (e < NE) { src = ei[e]; dst = ei[NE + e]; }
    else        { src = dst = e - NE; }
    int pos = atomicAdd(&cursor[dst], 1);
    csr_src[pos] = src;
}

// ---------------------------------------------------------------------------
// f32 GEMM: C[M,N] = A[M,K] @ B[K,N], row-major. 64x64 tile, 4x4 micro-tile.
// Optionally also emits a bf16 copy of C (gather table for the aggregate).
// ---------------------------------------------------------------------------
__global__ __launch_bounds__(256) void gemm_f32(const float* __restrict__ A,
                                                const float* __restrict__ B,
                                                float* __restrict__ C,
                                                unsigned short* __restrict__ Cb,
                                                int M, int N, int K)
{
    const int BM = 64, BN = 64, BK = 32;
    __shared__ float As[BK][BM];
    __shared__ float Bs[BK][BN];
    int tid = threadIdx.x;
    int tx = tid & 15, ty = tid >> 4;
    int row0 = blockIdx.x * BM, col0 = blockIdx.y * BN;
    float acc[4][4] = {};
    for (int k0 = 0; k0 < K; k0 += BK) {
        #pragma unroll
        for (int i = 0; i < 2; i++) {           // A tile: 64x32, transposed store
            int f4 = tid + i * 256;             // 0..511
            int r  = f4 >> 3;                   // 8 float4 per row
            int c4 = (f4 & 7) << 2;
            float4 v = make_float4(0.f, 0.f, 0.f, 0.f);
            int gr = row0 + r;
            if (gr < M) v = *(const float4*)&A[(size_t)gr * K + k0 + c4];
            As[c4 + 0][r] = v.x; As[c4 + 1][r] = v.y;
            As[c4 + 2][r] = v.z; As[c4 + 3][r] = v.w;
        }
        #pragma unroll
        for (int i = 0; i < 2; i++) {           // B tile: 32x64, direct
            int f4 = tid + i * 256;
            int r  = f4 >> 4;                   // 16 float4 per row
            int c4 = (f4 & 15) << 2;
            *(float4*)&Bs[r][c4] = *(const float4*)&B[(size_t)(k0 + r) * N + col0 + c4];
        }
        __syncthreads();
        #pragma unroll
        for (int k = 0; k < BK; k++) {
            float4 a = *(const float4*)&As[k][ty * 4];
            float4 b = *(const float4*)&Bs[k][tx * 4];
            float av[4] = {a.x, a.y, a.z, a.w};
            float bv[4] = {b.x, b.y, b.z, b.w};
            #pragma unroll
            for (int i = 0; i < 4; i++)
                #pragma unroll
                for (int j = 0; j < 4; j++)
                    acc[i][j] += av[i] * bv[j];
        }
        __syncthreads();
    }
    #pragma unroll
    for (int i = 0; i < 4; i++) {
        int gr = row0 + ty * 4 + i;
        if (gr < M) {
            float4 v = make_float4(acc[i][0], acc[i][1], acc[i][2], acc[i][3]);
            *(float4*)&C[(size_t)gr * N + col0 + tx * 4] = v;
            if (Cb) {
                ushort4 bv;
                bv.x = f2b(acc[i][0]); bv.y = f2b(acc[i][1]);
                bv.z = f2b(acc[i][2]); bv.w = f2b(acc[i][3]);
                *(ushort4*)&Cb[(size_t)gr * N + col0 + tx * 4] = bv;
            }
        }
    }
}

// ---------------------------------------------------------------------------
// Per-node attention coefficients: asrc[n,h] = dot(h[n,h,:], att_src[h,:])
// ---------------------------------------------------------------------------
template <int HEADS>
__global__ __launch_bounds__(256) void compute_alphas(const float* __restrict__ h,
                                                      const float* __restrict__ att_src,
                                                      const float* __restrict__ att_dst,
                                                      float* __restrict__ asrc,
                                                      float* __restrict__ adst, int n)
{
    const int CH  = HEADS * 128;
    const int PER = CH / 64;     // 4 (HEADS=2) or 2 (HEADS=1)
    const int RED = 128 / PER;   // lanes per head: 32 or 64
    int wid = threadIdx.x >> 6, lane = threadIdx.x & 63;
    int node = blockIdx.x * 4 + wid;
    if (node >= n) return;
    float ss = 0.f, sd = 0.f;
    if (PER == 4) {
        float4 hv = *(const float4*)&h[(size_t)node * CH + lane * 4];
        float4 vs = *(const float4*)&att_src[lane * 4];
        float4 vd = *(const float4*)&att_dst[lane * 4];
        ss = hv.x * vs.x + hv.y * vs.y + hv.z * vs.z + hv.w * vs.w;
        sd = hv.x * vd.x + hv.y * vd.y + hv.z * vd.z + hv.w * vd.w;
    } else {
        float2 hv = *(const float2*)&h[(size_t)node * CH + lane * 2];
        float2 vs = *(const float2*)&att_src[lane * 2];
        float2 vd = *(const float2*)&att_dst[lane * 2];
        ss = hv.x * vs.x + hv.y * vs.y;
        sd = hv.x * vd.x + hv.y * vd.y;
    }
    #pragma unroll
    for (int off = RED >> 1; off > 0; off >>= 1) {
        ss += __shfl_xor(ss, off);
        sd += __shfl_xor(sd, off);
    }
    if ((lane & (RED - 1)) == 0) {
        int head = lane / RED;
        asrc[node * HEADS + head] = ss;
        adst[node * HEADS + head] = sd;
    }
}

// ---------------------------------------------------------------------------
// GAT aggregation: per dst node -> softmax over in-edges -> weighted gather sum.
// Softmax logits fully f32; pass-3 messages gathered from the bf16 h-table
// (round-8 counters: byte/request throughput at ~3.7 TB/s is the limiter,
// per-wave MLP is not — the 8-deep unroll was a null result).
// ---------------------------------------------------------------------------
template <int HEADS>
__global__ __launch_bounds__(256) void gat_aggregate(const unsigned short* __restrict__ hb,
                                                     const float* __restrict__ asrc,
                                                     const float* __restrict__ adst,
                                                     const int* __restrict__ rowptr,
                                                     const int* __restrict__ csr_src,
                                                     const float* __restrict__ bias,
                                                     float* __restrict__ out, int n)
{
    const int CH   = HEADS * 128;
    const int PER  = CH / 64;          // channels per lane
    const int MAXE = 128;              // LDS-cached edge budget per node
    __shared__ float w_lds[4][MAXE * HEADS];
    __shared__ int   s_lds[4][MAXE];
    int wid = threadIdx.x >> 6, lane = threadIdx.x & 63;
    int node = blockIdx.x * 4 + wid;
    if (node >= n) return;

    int start = rowptr[node], end = rowptr[node + 1];
    int deg = end - start;
    bool fast = (deg <= MAXE);
    int head = (PER == 4) ? (lane >> 5) : 0;

    float ad[HEADS], m[HEADS], dsum[HEADS];
    #pragma unroll
    for (int hh = 0; hh < HEADS; hh++) { ad[hh] = adst[node * HEADS + hh]; m[hh] = -1e30f; dsum[hh] = 0.f; }

    // pass 1: e = leaky_relu(asrc[src]+adst[dst]); cache in LDS; wave max
    for (int base = 0; base < deg; base += 64) {
        int j = base + lane;
        if (j < deg) {
            int s = csr_src[start + j];
            if (fast) s_lds[wid][j] = s;
            #pragma unroll
            for (int hh = 0; hh < HEADS; hh++) {
                float v = asrc[s * HEADS + hh] + ad[hh];
                v = (v > 0.f) ? v : 0.2f * v;
                if (fast) w_lds[wid][j * HEADS + hh] = v;
                m[hh] = fmaxf(m[hh], v);
            }
        }
    }
    #pragma unroll
    for (int hh = 0; hh < HEADS; hh++)
        #pragma unroll
        for (int off = 32; off > 0; off >>= 1)
            m[hh] = fmaxf(m[hh], __shfl_xor(m[hh], off));

    // pass 2: exp(e - m), cache, wave sum
    for (int base = 0; base < deg; base += 64) {
        int j = base + lane;
        if (j < deg) {
            #pragma unroll
            for (int hh = 0; hh < HEADS; hh++) {
                float v;
                if (fast) v = w_lds[wid][j * HEADS + hh];
                else {
                    int s = csr_src[start + j];
                    v = asrc[s * HEADS + hh] + ad[hh];
                    v = (v > 0.f) ? v : 0.2f * v;
                }
                float ex = __expf(v - m[hh]);
                if (fast) w_lds[wid][j * HEADS + hh] = ex;
                dsum[hh] += ex;
            }
        }
    }
    #pragma unroll
    for (int hh = 0; hh < HEADS; hh++)
        #pragma unroll
        for (int off = 32; off > 0; off >>= 1)
            dsum[hh] += __shfl_xor(dsum[hh], off);

    float m_l    = (HEADS == 2 && head) ? m[HEADS - 1] : m[0];
    float ad_l   = (HEADS == 2 && head) ? ad[HEADS - 1] : ad[0];
    float inv_l  = 1.0f / ((HEADS == 2 && head) ? dsum[HEADS - 1] : dsum[0]);

    // pass 3: weighted gather-accumulate from bf16 table (half the bytes/lines)
    float acc[PER];
    #pragma unroll
    for (int p = 0; p < PER; p++) acc[p] = 0.f;

    auto edge_sw = [&](int j, int& s, float& wgt) {
        if (fast) {
            s   = s_lds[wid][j];
            wgt = w_lds[wid][j * HEADS + head] * inv_l;
        } else {
            s = csr_src[start + j];
            float v = asrc[s * HEADS + head] + ad_l;
            v = (v > 0.f) ? v : 0.2f * v;
            wgt = __expf(v - m_l) * inv_l;
        }
    };

    const int U = 8;
    int j = 0;
    for (; j + U <= deg; j += U) {
        int su[U]; float wu[U];
        #pragma unroll
        for (int u = 0; u < U; u++) edge_sw(j + u, su[u], wu[u]);
        if (PER == 4) {
            ushort4 hv[U];
            #pragma unroll
            for (int u = 0; u < U; u++)
                hv[u] = *(const ushort4*)&hb[(size_t)su[u] * CH + lane * 4];
            #pragma unroll
            for (int u = 0; u < U; u++) {
                acc[0] += wu[u] * b2f(hv[u].x); acc[1] += wu[u] * b2f(hv[u].y);
                acc[2] += wu[u] * b2f(hv[u].z); acc[3] += wu[u] * b2f(hv[u].w);
            }
        } else {
            ushort2 hv[U];
            #pragma unroll
            for (int u = 0; u < U; u++)
                hv[u] = *(const ushort2*)&hb[(size_t)su[u] * CH + lane * 2];
            #pragma unroll
            for (int u = 0; u < U; u++) {
                acc[0] += wu[u] * b2f(hv[u].x); acc[1] += wu[u] * b2f(hv[u].y);
            }
        }
    }
    for (; j < deg; j++) {
        int s; float wgt;
        edge_sw(j, s, wgt);
        if (PER == 4) {
            ushort4 hv = *(const ushort4*)&hb[(size_t)s * CH + lane * 4];
            acc[0] += wgt * b2f(hv.x); acc[1] += wgt * b2f(hv.y);
            acc[2] += wgt * b2f(hv.z); acc[3] += wgt * b2f(hv.w);
        } else {
            ushort2 hv = *(const ushort2*)&hb[(size_t)s * CH + lane * 2];
            acc[0] += wgt * b2f(hv.x); acc[1] += wgt * b2f(hv.y);
        }
    }

    #pragma unroll
    for (int p = 0; p < PER; p++) {
        float v = acc[p] + bias[lane * PER + p];
        out[(size_t)node * CH + lane * PER + p] = fmaxf(v, 0.f);
    }
}

// ---------------------------------------------------------------------------
// Sorted-batch pooling: binary-search graph boundaries, then one block per
// graph reduces its contiguous node range (no atomics; replaces 6.4M-atomic
// pool_kernel whose write-through traffic was ~101 MB).
// ---------------------------------------------------------------------------
__global__ void find_bounds(const int* __restrict__ batch, int* __restrict__ bstart)
{
    int g = blockIdx.x * 256 + threadIdx.x;
    if (g > NG) return;
    if (g == NG) { bstart[NG] = NN; return; }
    int lo = 0, hi = NN;
    while (lo < hi) { int mid = (lo + hi) >> 1; if (batch[mid] < g) lo = mid + 1; else hi = mid; }
    bstart[g] = lo;
}

__global__ __launch_bounds__(256) void pool_seg(const float* __restrict__ h,
                                                const int* __restrict__ bstart,
                                                float* __restrict__ pooled)
{
    __shared__ float2 part[4][64];
    int g = blockIdx.x;
    int start = bstart[g], end = bstart[g + 1];
    int lane = threadIdx.x & 63, w = threadIdx.x >> 6;
    float2 acc = make_float2(0.f, 0.f);
    for (int i = start + w; i < end; i += 4) {
        float2 v = *(const float2*)&h[(size_t)i * 128 + lane * 2];
        acc.x += v.x; acc.y += v.y;
    }
    part[w][lane] = acc;
    __syncthreads();
    if (w == 0) {
        float2 s = part[0][lane];
        s.x += part[1][lane].x + part[2][lane].x + part[3][lane].x;
        s.y += part[1][lane].y + part[2][lane].y + part[3][lane].y;
        float invc = 1.0f / fmaxf((float)(end - start), 1.0f);
        pooled[g * 128 + lane * 2 + 0] = s.x * invc;
        pooled[g * 128 + lane * 2 + 1] = s.y * invc;
    }
}

__global__ __launch_bounds__(64) void head_mlp(const float* __restrict__ pooled,
                                               const float* __restrict__ lw1,
                                               const float* __restrict__ lb1,
                                               const float* __restrict__ lw2,
                                               const float* __restrict__ lb2,
                                               float* __restrict__ out)
{
    int g = blockIdx.x, lane = threadIdx.x;
    __shared__ float p[128];
    p[lane]      = pooled[g * 128 + lane];
    p[lane + 64] = pooled[g * 128 + lane + 64];
    __syncthreads();
    float z = lb1[lane];
    #pragma unroll 8
    for (int k = 0; k < 128; k++) z += p[k] * lw1[k * 64 + lane];
    z = fmaxf(z, 0.f);
    float v = z * lw2[lane];
    #pragma unroll
    for (int off = 32; off > 0; off >>= 1) v += __shfl_xor(v, off);
    if (lane == 0) out[g] = v + lb2[0];
}

// ---------------------------------------------------------------------------
extern "C" void kernel_launch(void* const* d_in, const int* in_sizes, int n_in,
                              void* d_out, int out_size, void* d_ws, size_t ws_size,
                              hipStream_t stream)
{
    const float* x      = (const float*)d_in[0];
    const int*   ei_raw = (const int*)d_in[1];
    const int*   bat_raw= (const int*)d_in[2];
    const float* W1   = (const float*)d_in[4];
    const float* as1  = (const float*)d_in[5];
    const float* ad1  = (const float*)d_in[6];
    const float* b1   = (const float*)d_in[7];
    const float* W2   = (const float*)d_in[8];
    const float* as2  = (const float*)d_in[9];
    const float* ad2  = (const float*)d_in[10];
    const float* b2   = (const float*)d_in[11];
    const float* lw1  = (const float*)d_in[12];
    const float* lb1  = (const float*)d_in[13];
    const float* lw2  = (const float*)d_in[14];
    const float* lb2  = (const float*)d_in[15];
    float* out = (float*)d_out;

    char* w = (char*)d_ws;
    auto alloc = [&](size_t bytes) { char* p = w; w += (bytes + 255) & ~size_t(255); return p; };
    float*          h1    = (float*)alloc((size_t)NN * 256 * 4);
    float*          o1    = (float*)alloc((size_t)NN * 256 * 4);
    float*          h2    = (float*)alloc((size_t)NN * 128 * 4);
    float*          o2    = (float*)alloc((size_t)NN * 128 * 4);
    unsigned short* h1b   = (unsigned short*)alloc((size_t)NN * 256 * 2);
    unsigned short* h2b   = (unsigned short*)alloc((size_t)NN * 128 * 2);
    float* asrc1 = (float*)alloc((size_t)NN * 2 * 4);
    float* adst1 = (float*)alloc((size_t)NN * 2 * 4);
    float* asrc2 = (float*)alloc((size_t)NN * 4);
    float* adst2 = (float*)alloc((size_t)NN * 4);
    int*   cnts  = (int*)alloc((size_t)NN * 4);
    int*   rowp  = (int*)alloc((size_t)(NN + 4) * 4);
    int*   curs  = (int*)alloc((size_t)NN * 4);
    int*   csr   = (int*)alloc((size_t)NEP * 4);
    float* pooled= (float*)alloc((size_t)NG * 128 * 4);
    int*   bstart= (int*)alloc((size_t)(NG + 4) * 4);
    int*   ei32  = (int*)alloc((size_t)2 * NE * 4);
    int*   bat32 = (int*)alloc((size_t)NN * 4);
    int*   flags = (int*)alloc(2 * 4);

    // normalize integer inputs (int64 or int32 -> int32)
    detect_i64<<<1, 256, 0, stream>>>(ei_raw, 2 * NE, &flags[0]);
    detect_i64<<<1, 256, 0, stream>>>(bat_raw, NN, &flags[1]);
    cvt_idx<<<(2 * NE + 255) / 256, 256, 0, stream>>>(ei_raw, &flags[0], ei32, 2 * NE);
    cvt_idx<<<(NN + 255) / 256, 256, 0, stream>>>(bat_raw, &flags[1], bat32, NN);

    // CSR build (shared by both layers)
    hipMemsetAsync(cnts, 0, NN * 4, stream);
    edge_hist<<<(NEP + 255) / 256, 256, 0, stream>>>(ei32, cnts);
    scan_counts<<<1, 1024, 0, stream>>>(cnts, rowp, NN);
    copy_int<<<(NN + 255) / 256, 256, 0, stream>>>(rowp, curs, NN);
    edge_scatter<<<(NEP + 255) / 256, 256, 0, stream>>>(ei32, curs, csr);

    // layer 1: h1 = x@W1 (+bf16 copy) ; alphas(f32) ; aggregate(bf16 gather)
    gemm_f32<<<dim3((NN + 63) / 64, 4), 256, 0, stream>>>(x, W1, h1, h1b, NN, 256, 128);
    compute_alphas<2><<<(NN + 3) / 4, 256, 0, stream>>>(h1, as1, ad1, asrc1, adst1, NN);
    gat_aggregate<2><<<(NN + 3) / 4, 256, 0, stream>>>(h1b, asrc1, adst1, rowp, csr, b1, o1, NN);

    // layer 2
    gemm_f32<<<dim3((NN + 63) / 64, 2), 256, 0, stream>>>(o1, W2, h2, h2b, NN, 128, 256);
    compute_alphas<1><<<(NN + 3) / 4, 256, 0, stream>>>(h2, as2, ad2, asrc2, adst2, NN);
    gat_aggregate<1><<<(NN + 3) / 4, 256, 0, stream>>>(h2b, asrc2, adst2, rowp, csr, b2, o2, NN);

    // pool (sorted batch -> segmented, no atomics) + head
    find_bounds<<<(NG + 1 + 255) / 256, 256, 0, stream>>>(bat32, bstart);
    pool_seg<<<NG, 256, 0, stream>>>(o2, bstart, pooled);
    head_mlp<<<NG, 64, 0, stream>>>(pooled, lw1, lb1, lw2, lb2, out);
}

// Round 12
// 491.701 us; speedup vs baseline: 1.4280x; 1.0364x over previous
//
#include <hip/hip_runtime.h>

// Problem constants (fixed by the reference file)
#define NN 50000
#define NE 800000
#define NEP (NN + NE)      // edges + self-loops = 850000
#define NG 1024

// bf16 helpers (internal approximation only; reference is all-f32)
__device__ inline unsigned short f2b(float f) {
    unsigned int u = __float_as_uint(f);
    unsigned int r = (u + 0x7FFFu + ((u >> 16) & 1u)) >> 16;   // round-nearest-even
    return (unsigned short)r;
}
__device__ inline float b2f(unsigned short b) {
    return __uint_as_float(((unsigned int)b) << 16);
}

// ---------------------------------------------------------------------------
// int64-vs-int32 input format probe + normalization.
// ---------------------------------------------------------------------------
__global__ void detect_i64(const int* __restrict__ raw, int n32, int* __restrict__ flag)
{
    __shared__ int nz;
    int tid = threadIdx.x;          // single block of 256
    if (tid == 0) nz = 0;
    __syncthreads();
    int cnt = 0;
    for (int i = tid; i < 1024; i += 256) {
        int p = n32 - 2048 + 2 * i + 1;          // odd int32 positions in tail
        if (p >= 0 && p < n32 && raw[p] != 0) cnt++;
    }
    atomicAdd(&nz, cnt);
    __syncthreads();
    if (tid == 0) flag[0] = (nz == 0) ? 1 : 0;   // 1 -> int64 layout
}

__global__ void cvt_idx(const int* __restrict__ raw, const int* __restrict__ flag,
                        int* __restrict__ out, int n)
{
    int i = blockIdx.x * 256 + threadIdx.x;
    if (i >= n) return;
    out[i] = flag[0] ? raw[2 * i] : raw[i];      // low word if int64
}

// ---------------------------------------------------------------------------
// CSR build: histogram -> exclusive scan -> scatter (dst-indexed)
// ---------------------------------------------------------------------------
__global__ void edge_hist(const int* __restrict__ ei, int* __restrict__ cnt)
{
    int e = blockIdx.x * 256 + threadIdx.x;
    if (e >= NEP) return;
    int dst = (e < NE) ? ei[NE + e] : (e - NE);
    atomicAdd(&cnt[dst], 1);
}

__global__ __launch_bounds__(1024) void scan_counts(const int* __restrict__ cnt,
                                                    int* __restrict__ rowptr, int n)
{
    __shared__ int wsums[16];
    __shared__ int carry_s;
    int tid = threadIdx.x, lane = tid & 63, wid = tid >> 6;
    if (tid == 0) carry_s = 0;
    __syncthreads();
    for (int base = 0; base < n; base += 1024) {
        int i = base + tid;
        int v = (i < n) ? cnt[i] : 0;
        int s = v;
        #pragma unroll
        for (int off = 1; off < 64; off <<= 1) {
            int t = __shfl_up(s, off);
            if (lane >= off) s += t;
        }
        if (lane == 63) wsums[wid] = s;
        __syncthreads();
        if (wid == 0 && lane < 16) {
            int ws = wsums[lane];
            #pragma unroll
            for (int off = 1; off < 16; off <<= 1) {
                int t = __shfl_up(ws, off);
                if (lane >= off) ws += t;
            }
            wsums[lane] = ws;   // inclusive scan of wave sums
        }
        __syncthreads();
        int wave_off = (wid == 0) ? 0 : wsums[wid - 1];
        int carry = carry_s;
        if (i < n) rowptr[i] = carry + wave_off + s - v;   // exclusive
        int total = wsums[15];
        __syncthreads();   // all reads of carry_s/wsums done
        if (tid == 0) carry_s = carry + total;
        __syncthreads();   // carry_s updated before next chunk
    }
    if (tid == 0) rowptr[n] = carry_s;
}

__global__ void copy_int(const int* __restrict__ a, int* __restrict__ b, int n)
{
    int i = blockIdx.x * 256 + threadIdx.x;
    if (i < n) b[i] = a[i];
}

__global__ void edge_scatter(const int* __restrict__ ei, int* __restrict__ cursor,
                             int* __restrict__ csr_src)
{
    int e = blockIdx.x * 256 + threadIdx.x;
    if (e >= NEP) return;
    int src, dst;
    if (e < NE) { src = ei[e]; dst = ei[NE + e]; }
    else        { src = dst = e - NE; }
    int pos = atomicAdd(&cursor[dst], 1);
    csr_src[pos] = src;
}

// ---------------------------------------------------------------------------
// Fused GEMM: Cb(bf16) = A[M,K] @ B[K,N], 128x128 tile, 8x8 micro-tile
// (old 64x64/4x4 was LDS-throughput-bound at FMA:read=2:1; this is 4:1).
// Epilogue fuses the attention dots: asrc[r,h] += acc·att_src (16-lane
// shuffle reduce + 1 atomic per row per block). No f32 C store — nothing
// downstream consumes it (alphas fused here, messages read bf16).
// ---------------------------------------------------------------------------
template <int HEADS>
__global__ __launch_bounds__(256) void gemm_fused(const float* __restrict__ A,
                                                  const float* __restrict__ B,
                                                  unsigned short* __restrict__ Cb,
                                                  const float* __restrict__ att_src,
                                                  const float* __restrict__ att_dst,
                                                  float* __restrict__ asrc,
                                                  float* __restrict__ adst,
                                                  int M, int N, int K)
{
    const int BM = 128, BN = 128, BK = 16;
    __shared__ float As[BK][BM];
    __shared__ float Bs[BK][BN];
    int tid = threadIdx.x;
    int tx = tid & 15, ty = tid >> 4;
    int row0 = blockIdx.x * BM, col0 = blockIdx.y * BN;
    float acc[8][8] = {};
    for (int k0 = 0; k0 < K; k0 += BK) {
        #pragma unroll
        for (int i = 0; i < 2; i++) {            // A tile: 128x16, transposed store
            int f4 = tid + i * 256;              // 0..511
            int r  = f4 >> 2;                    // 4 float4 per row
            int c4 = (f4 & 3) << 2;
            float4 v = make_float4(0.f, 0.f, 0.f, 0.f);
            int gr = row0 + r;
            if (gr < M) v = *(const float4*)&A[(size_t)gr * K + k0 + c4];
            As[c4 + 0][r] = v.x; As[c4 + 1][r] = v.y;
            As[c4 + 2][r] = v.z; As[c4 + 3][r] = v.w;
        }
        #pragma unroll
        for (int i = 0; i < 2; i++) {            // B tile: 16x128, direct
            int f4 = tid + i * 256;
            int r  = f4 >> 5;                    // 32 float4 per row
            int c4 = (f4 & 31) << 2;
            *(float4*)&Bs[r][c4] = *(const float4*)&B[(size_t)(k0 + r) * N + col0 + c4];
        }
        __syncthreads();
        #pragma unroll
        for (int k = 0; k < BK; k++) {
            float av[8], bv[8];
            *(float4*)&av[0] = *(const float4*)&As[k][ty * 8];
            *(float4*)&av[4] = *(const float4*)&As[k][ty * 8 + 4];
            *(float4*)&bv[0] = *(const float4*)&Bs[k][tx * 8];
            *(float4*)&bv[4] = *(const float4*)&Bs[k][tx * 8 + 4];
            #pragma unroll
            for (int i = 0; i < 8; i++)
                #pragma unroll
                for (int j = 0; j < 8; j++)
                    acc[i][j] += av[i] * bv[j];
        }
        __syncthreads();
    }

    // epilogue: att values for this thread's 8 columns (col block is within one head)
    float vs[8], vd[8];
    #pragma unroll
    for (int j = 0; j < 8; j++) {
        vs[j] = att_src[col0 + tx * 8 + j];
        vd[j] = att_dst[col0 + tx * 8 + j];
    }
    int head = col0 >> 7;                        // BN=128-aligned => uniform per block
    #pragma unroll
    for (int i = 0; i < 8; i++) {
        int gr = row0 + ty * 8 + i;
        if (gr < M) {                            // uniform within the 16-lane group
            float ps = 0.f, pd = 0.f;
            #pragma unroll
            for (int j = 0; j < 8; j++) { ps += acc[i][j] * vs[j]; pd += acc[i][j] * vd[j]; }
            #pragma unroll
            for (int off = 8; off > 0; off >>= 1) {
                ps += __shfl_xor(ps, off);
                pd += __shfl_xor(pd, off);
            }
            if (tx == 0) {
                atomicAdd(&asrc[gr * HEADS + head], ps);
                atomicAdd(&adst[gr * HEADS + head], pd);
            }
            #pragma unroll
            for (int j = 0; j < 8; j += 4) {
                ushort4 bvv;
                bvv.x = f2b(acc[i][j + 0]); bvv.y = f2b(acc[i][j + 1]);
                bvv.z = f2b(acc[i][j + 2]); bvv.w = f2b(acc[i][j + 3]);
                *(ushort4*)&Cb[(size_t)gr * N + col0 + tx * 8 + j] = bvv;
            }
        }
    }
}

// ---------------------------------------------------------------------------
// GAT aggregation: per dst node -> softmax over in-edges -> weighted gather sum.
// Softmax logits fully f32; pass-3 messages gathered from the bf16 h-table.
// ---------------------------------------------------------------------------
template <int HEADS>
__global__ __launch_bounds__(256) void gat_aggregate(const unsigned short* __restrict__ hb,
                                                     const float* __restrict__ asrc,
                                                     const float* __restrict__ adst,
                                                     const int* __restrict__ rowptr,
                                                     const int* __restrict__ csr_src,
                                                     const float* __restrict__ bias,
                                                     float* __restrict__ out, int n)
{
    const int CH   = HEADS * 128;
    const int PER  = CH / 64;          // channels per lane
    const int MAXE = 128;              // LDS-cached edge budget per node
    __shared__ float w_lds[4][MAXE * HEADS];
    __shared__ int   s_lds[4][MAXE];
    int wid = threadIdx.x >> 6, lane = threadIdx.x & 63;
    int node = blockIdx.x * 4 + wid;
    if (node >= n) return;

    int start = rowptr[node], end = rowptr[node + 1];
    int deg = end - start;
    bool fast = (deg <= MAXE);
    int head = (PER == 4) ? (lane >> 5) : 0;

    float ad[HEADS], m[HEADS], dsum[HEADS];
    #pragma unroll
    for (int hh = 0; hh < HEADS; hh++) { ad[hh] = adst[node * HEADS + hh]; m[hh] = -1e30f; dsum[hh] = 0.f; }

    // pass 1: e = leaky_relu(asrc[src]+adst[dst]); cache in LDS; wave max
    for (int base = 0; base < deg; base += 64) {
        int j = base + lane;
        if (j < deg) {
            int s = csr_src[start + j];
            if (fast) s_lds[wid][j] = s;
            #pragma unroll
            for (int hh = 0; hh < HEADS; hh++) {
                float v = asrc[s * HEADS + hh] + ad[hh];
                v = (v > 0.f) ? v : 0.2f * v;
                if (fast) w_lds[wid][j * HEADS + hh] = v;
                m[hh] = fmaxf(m[hh], v);
            }
        }
    }
    #pragma unroll
    for (int hh = 0; hh < HEADS; hh++)
        #pragma unroll
        for (int off = 32; off > 0; off >>= 1)
            m[hh] = fmaxf(m[hh], __shfl_xor(m[hh], off));

    // pass 2: exp(e - m), cache, wave sum
    for (int base = 0; base < deg; base += 64) {
        int j = base + lane;
        if (j < deg) {
            #pragma unroll
            for (int hh = 0; hh < HEADS; hh++) {
                float v;
                if (fast) v = w_lds[wid][j * HEADS + hh];
                else {
                    int s = csr_src[start + j];
                    v = asrc[s * HEADS + hh] + ad[hh];
                    v = (v > 0.f) ? v : 0.2f * v;
                }
                float ex = __expf(v - m[hh]);
                if (fast) w_lds[wid][j * HEADS + hh] = ex;
                dsum[hh] += ex;
            }
        }
    }
    #pragma unroll
    for (int hh = 0; hh < HEADS; hh++)
        #pragma unroll
        for (int off = 32; off > 0; off >>= 1)
            dsum[hh] += __shfl_xor(dsum[hh], off);

    float m_l    = (HEADS == 2 && head) ? m[HEADS - 1] : m[0];
    float ad_l   = (HEADS == 2 && head) ? ad[HEADS - 1] : ad[0];
    float inv_l  = 1.0f / ((HEADS == 2 && head) ? dsum[HEADS - 1] : dsum[0]);

    // pass 3: weighted gather-accumulate from bf16 table (half the bytes/lines)
    float acc[PER];
    #pragma unroll
    for (int p = 0; p < PER; p++) acc[p] = 0.f;

    auto edge_sw = [&](int j, int& s, float& wgt) {
        if (fast) {
            s   = s_lds[wid][j];
            wgt = w_lds[wid][j * HEADS + head] * inv_l;
        } else {
            s = csr_src[start + j];
            float v = asrc[s * HEADS + head] + ad_l;
            v = (v > 0.f) ? v : 0.2f * v;
            wgt = __expf(v - m_l) * inv_l;
        }
    };

    const int U = 8;
    int j = 0;
    for (; j + U <= deg; j += U) {
        int su[U]; float wu[U];
        #pragma unroll
        for (int u = 0; u < U; u++) edge_sw(j + u, su[u], wu[u]);
        if (PER == 4) {
            ushort4 hv[U];
            #pragma unroll
            for (int u = 0; u < U; u++)
                hv[u] = *(const ushort4*)&hb[(size_t)su[u] * CH + lane * 4];
            #pragma unroll
            for (int u = 0; u < U; u++) {
                acc[0] += wu[u] * b2f(hv[u].x); acc[1] += wu[u] * b2f(hv[u].y);
                acc[2] += wu[u] * b2f(hv[u].z); acc[3] += wu[u] * b2f(hv[u].w);
            }
        } else {
            ushort2 hv[U];
            #pragma unroll
            for (int u = 0; u < U; u++)
                hv[u] = *(const ushort2*)&hb[(size_t)su[u] * CH + lane * 2];
            #pragma unroll
            for (int u = 0; u < U; u++) {
                acc[0] += wu[u] * b2f(hv[u].x); acc[1] += wu[u] * b2f(hv[u].y);
            }
        }
    }
    for (; j < deg; j++) {
        int s; float wgt;
        edge_sw(j, s, wgt);
        if (PER == 4) {
            ushort4 hv = *(const ushort4*)&hb[(size_t)s * CH + lane * 4];
            acc[0] += wgt * b2f(hv.x); acc[1] += wgt * b2f(hv.y);
            acc[2] += wgt * b2f(hv.z); acc[3] += wgt * b2f(hv.w);
        } else {
            ushort2 hv = *(const ushort2*)&hb[(size_t)s * CH + lane * 2];
            acc[0] += wgt * b2f(hv.x); acc[1] += wgt * b2f(hv.y);
        }
    }

    #pragma unroll
    for (int p = 0; p < PER; p++) {
        float v = acc[p] + bias[lane * PER + p];
        out[(size_t)node * CH + lane * PER + p] = fmaxf(v, 0.f);
    }
}

// ---------------------------------------------------------------------------
// Sorted-batch pooling + MLP head
// ---------------------------------------------------------------------------
__global__ void find_bounds(const int* __restrict__ batch, int* __restrict__ bstart)
{
    int g = blockIdx.x * 256 + threadIdx.x;
    if (g > NG) return;
    if (g == NG) { bstart[NG] = NN; return; }
    int lo = 0, hi = NN;
    while (lo < hi) { int mid = (lo + hi) >> 1; if (batch[mid] < g) lo = mid + 1; else hi = mid; }
    bstart[g] = lo;
}

__global__ __launch_bounds__(256) void pool_seg(const float* __restrict__ h,
                                                const int* __restrict__ bstart,
                                                float* __restrict__ pooled)
{
    __shared__ float2 part[4][64];
    int g = blockIdx.x;
    int start = bstart[g], end = bstart[g + 1];
    int lane = threadIdx.x & 63, w = threadIdx.x >> 6;
    float2 acc = make_float2(0.f, 0.f);
    for (int i = start + w; i < end; i += 4) {
        float2 v = *(const float2*)&h[(size_t)i * 128 + lane * 2];
        acc.x += v.x; acc.y += v.y;
    }
    part[w][lane] = acc;
    __syncthreads();
    if (w == 0) {
        float2 s = part[0][lane];
        s.x += part[1][lane].x + part[2][lane].x + part[3][lane].x;
        s.y += part[1][lane].y + part[2][lane].y + part[3][lane].y;
        float invc = 1.0f / fmaxf((float)(end - start), 1.0f);
        pooled[g * 128 + lane * 2 + 0] = s.x * invc;
        pooled[g * 128 + lane * 2 + 1] = s.y * invc;
    }
}

__global__ __launch_bounds__(64) void head_mlp(const float* __restrict__ pooled,
                                               const float* __restrict__ lw1,
                                               const float* __restrict__ lb1,
                                               const float* __restrict__ lw2,
                                               const float* __restrict__ lb2,
                                               float* __restrict__ out)
{
    int g = blockIdx.x, lane = threadIdx.x;
    __shared__ float p[128];
    p[lane]      = pooled[g * 128 + lane];
    p[lane + 64] = pooled[g * 128 + lane + 64];
    __syncthreads();
    float z = lb1[lane];
    #pragma unroll 8
    for (int k = 0; k < 128; k++) z += p[k] * lw1[k * 64 + lane];
    z = fmaxf(z, 0.f);
    float v = z * lw2[lane];
    #pragma unroll
    for (int off = 32; off > 0; off >>= 1) v += __shfl_xor(v, off);
    if (lane == 0) out[g] = v + lb2[0];
}

// ---------------------------------------------------------------------------
extern "C" void kernel_launch(void* const* d_in, const int* in_sizes, int n_in,
                              void* d_out, int out_size, void* d_ws, size_t ws_size,
                              hipStream_t stream)
{
    const float* x      = (const float*)d_in[0];
    const int*   ei_raw = (const int*)d_in[1];
    const int*   bat_raw= (const int*)d_in[2];
    const float* W1   = (const float*)d_in[4];
    const float* as1  = (const float*)d_in[5];
    const float* ad1  = (const float*)d_in[6];
    const float* b1   = (const float*)d_in[7];
    const float* W2   = (const float*)d_in[8];
    const float* as2  = (const float*)d_in[9];
    const float* ad2  = (const float*)d_in[10];
    const float* b2   = (const float*)d_in[11];
    const float* lw1  = (const float*)d_in[12];
    const float* lb1  = (const float*)d_in[13];
    const float* lw2  = (const float*)d_in[14];
    const float* lb2  = (const float*)d_in[15];
    float* out = (float*)d_out;

    char* w = (char*)d_ws;
    auto alloc = [&](size_t bytes) { char* p = w; w += (bytes + 255) & ~size_t(255); return p; };
    float*          o1    = (float*)alloc((size_t)NN * 256 * 4);
    float*          o2    = (float*)alloc((size_t)NN * 128 * 4);
    unsigned short* h1b   = (unsigned short*)alloc((size_t)NN * 256 * 2);
    unsigned short* h2b   = (unsigned short*)alloc((size_t)NN * 128 * 2);
    // alpha block: asrc1[NN*2], adst1[NN*2], asrc2[NN], adst2[NN] — one memset
    float* alph  = (float*)alloc((size_t)NN * 6 * 4);
    float* asrc1 = alph;
    float* adst1 = alph + (size_t)NN * 2;
    float* asrc2 = alph + (size_t)NN * 4;
    float* adst2 = alph + (size_t)NN * 5;
    int*   cnts  = (int*)alloc((size_t)NN * 4);
    int*   rowp  = (int*)alloc((size_t)(NN + 4) * 4);
    int*   curs  = (int*)alloc((size_t)NN * 4);
    int*   csr   = (int*)alloc((size_t)NEP * 4);
    float* pooled= (float*)alloc((size_t)NG * 128 * 4);
    int*   bstart= (int*)alloc((size_t)(NG + 4) * 4);
    int*   ei32  = (int*)alloc((size_t)2 * NE * 4);
    int*   bat32 = (int*)alloc((size_t)NN * 4);
    int*   flags = (int*)alloc(2 * 4);

    // normalize integer inputs (int64 or int32 -> int32)
    detect_i64<<<1, 256, 0, stream>>>(ei_raw, 2 * NE, &flags[0]);
    detect_i64<<<1, 256, 0, stream>>>(bat_raw, NN, &flags[1]);
    cvt_idx<<<(2 * NE + 255) / 256, 256, 0, stream>>>(ei_raw, &flags[0], ei32, 2 * NE);
    cvt_idx<<<(NN + 255) / 256, 256, 0, stream>>>(bat_raw, &flags[1], bat32, NN);

    // CSR build (shared by both layers)
    hipMemsetAsync(cnts, 0, NN * 4, stream);
    hipMemsetAsync(alph, 0, (size_t)NN * 6 * 4, stream);
    edge_hist<<<(NEP + 255) / 256, 256, 0, stream>>>(ei32, cnts);
    scan_counts<<<1, 1024, 0, stream>>>(cnts, rowp, NN);
    copy_int<<<(NN + 255) / 256, 256, 0, stream>>>(rowp, curs, NN);
    edge_scatter<<<(NEP + 255) / 256, 256, 0, stream>>>(ei32, curs, csr);

    // layer 1: fused GEMM (bf16 h + alpha dots) ; aggregate
    gemm_fused<2><<<dim3((NN + 127) / 128, 2), 256, 0, stream>>>(
        x, W1, h1b, as1, ad1, asrc1, adst1, NN, 256, 128);
    gat_aggregate<2><<<(NN + 3) / 4, 256, 0, stream>>>(h1b, asrc1, adst1, rowp, csr, b1, o1, NN);

    // layer 2
    gemm_fused<1><<<dim3((NN + 127) / 128, 1), 256, 0, stream>>>(
        o1, W2, h2b, as2, ad2, asrc2, adst2, NN, 128, 256);
    gat_aggregate<1><<<(NN + 3) / 4, 256, 0, stream>>>(h2b, asrc2, adst2, rowp, csr, b2, o2, NN);

    // pool (sorted batch -> segmented, no atomics) + head
    find_bounds<<<(NG + 1 + 255) / 256, 256, 0, stream>>>(bat32, bstart);
    pool_seg<<<NG, 256, 0, stream>>>(o2, bstart, pooled);
    head_mlp<<<NG, 64, 0, stream>>>(pooled, lw1, lb1, lw2, lb2, out);
}

// Round 13
// 435.705 us; speedup vs baseline: 1.6115x; 1.1285x over previous
//
#include <hip/hip_runtime.h>

// Problem constants (fixed by the reference file)
#define NN 50000
#define NE 800000
#define NEP (NN + NE)      // edges + self-loops = 850000
#define NG 1024

typedef short bf16x8 __attribute__((ext_vector_type(8)));   // 8 bf16 (4 VGPRs)
typedef float f32x4  __attribute__((ext_vector_type(4)));   // MFMA accum

// bf16 helpers (internal approximation only; reference is all-f32)
__device__ inline unsigned short f2b(float f) {
    unsigned int u = __float_as_uint(f);
    unsigned int r = (u + 0x7FFFu + ((u >> 16) & 1u)) >> 16;   // round-nearest-even
    return (unsigned short)r;
}
__device__ inline float b2f(unsigned short b) {
    return __uint_as_float(((unsigned int)b) << 16);
}

// ---------------------------------------------------------------------------
// int64-vs-int32 input format probe + normalization.
// ---------------------------------------------------------------------------
__global__ void detect_i64(const int* __restrict__ raw, int n32, int* __restrict__ flag)
{
    __shared__ int nz;
    int tid = threadIdx.x;          // single block of 256
    if (tid == 0) nz = 0;
    __syncthreads();
    int cnt = 0;
    for (int i = tid; i < 1024; i += 256) {
        int p = n32 - 2048 + 2 * i + 1;          // odd int32 positions in tail
        if (p >= 0 && p < n32 && raw[p] != 0) cnt++;
    }
    atomicAdd(&nz, cnt);
    __syncthreads();
    if (tid == 0) flag[0] = (nz == 0) ? 1 : 0;   // 1 -> int64 layout
}

__global__ void cvt_idx(const int* __restrict__ raw, const int* __restrict__ flag,
                        int* __restrict__ out, int n)
{
    int i = blockIdx.x * 256 + threadIdx.x;
    if (i >= n) return;
    out[i] = flag[0] ? raw[2 * i] : raw[i];      // low word if int64
}

// ---------------------------------------------------------------------------
// CSR build: histogram -> exclusive scan (also emits cursor) -> scatter.
// hist/scatter read the raw edge buffer directly (flag-selected stride).
// ---------------------------------------------------------------------------
__global__ void edge_hist(const int* __restrict__ raw, const int* __restrict__ flag,
                          int* __restrict__ cnt)
{
    int e = blockIdx.x * 256 + threadIdx.x;
    if (e >= NEP) return;
    int f = flag[0];
    int dst = (e < NE) ? (f ? raw[2 * (NE + e)] : raw[NE + e]) : (e - NE);
    atomicAdd(&cnt[dst], 1);
}

__global__ __launch_bounds__(1024) void scan_counts(const int* __restrict__ cnt,
                                                    int* __restrict__ rowptr,
                                                    int* __restrict__ curs, int n)
{
    __shared__ int wsums[16];
    __shared__ int carry_s;
    int tid = threadIdx.x, lane = tid & 63, wid = tid >> 6;
    if (tid == 0) carry_s = 0;
    __syncthreads();
    for (int base = 0; base < n; base += 1024) {
        int i = base + tid;
        int v = (i < n) ? cnt[i] : 0;
        int s = v;
        #pragma unroll
        for (int off = 1; off < 64; off <<= 1) {
            int t = __shfl_up(s, off);
            if (lane >= off) s += t;
        }
        if (lane == 63) wsums[wid] = s;
        __syncthreads();
        if (wid == 0 && lane < 16) {
            int ws = wsums[lane];
            #pragma unroll
            for (int off = 1; off < 16; off <<= 1) {
                int t = __shfl_up(ws, off);
                if (lane >= off) ws += t;
            }
            wsums[lane] = ws;   // inclusive scan of wave sums
        }
        __syncthreads();
        int wave_off = (wid == 0) ? 0 : wsums[wid - 1];
        int carry = carry_s;
        if (i < n) {
            int ex = carry + wave_off + s - v;   // exclusive
            rowptr[i] = ex;
            curs[i]   = ex;
        }
        int total = wsums[15];
        __syncthreads();   // all reads of carry_s/wsums done
        if (tid == 0) carry_s = carry + total;
        __syncthreads();   // carry_s updated before next chunk
    }
    if (tid == 0) rowptr[n] = carry_s;
}

__global__ void edge_scatter(const int* __restrict__ raw, const int* __restrict__ flag,
                             int* __restrict__ cursor, int* __restrict__ csr_src)
{
    int e = blockIdx.x * 256 + threadIdx.x;
    if (e >= NEP) return;
    int f = flag[0];
    int src, dst;
    if (e < NE) {
        src = f ? raw[2 * e] : raw[e];
        dst = f ? raw[2 * (NE + e)] : raw[NE + e];
    } else { src = dst = e - NE; }
    int pos = atomicAdd(&cursor[dst], 1);
    csr_src[pos] = src;
}

// ---------------------------------------------------------------------------
// bf16 pre-casts: x -> xb ; W[K,N] -> Wt[N,K] (transposed for GEMM staging)
// ---------------------------------------------------------------------------
__global__ void cast_bf16_vec(const float* __restrict__ in, unsigned short* __restrict__ out,
                              int n4)
{
    int i = blockIdx.x * 256 + threadIdx.x;
    if (i >= n4) return;
    float4 v = ((const float4*)in)[i];
    ushort4 o;
    o.x = f2b(v.x); o.y = f2b(v.y); o.z = f2b(v.z); o.w = f2b(v.w);
    ((ushort4*)out)[i] = o;
}

__global__ void cast_transpose(const float* __restrict__ W, unsigned short* __restrict__ Wt,
                               int K, int N)
{
    int idx = blockIdx.x * 256 + threadIdx.x;
    if (idx >= K * N) return;
    int n = idx / K, k = idx - n * K;            // Wt[n][k] = W[k][n]
    Wt[idx] = f2b(W[(size_t)k * N + n]);
}

// ---------------------------------------------------------------------------
// MFMA bf16 GEMM: Cb[M,N](bf16) = A[M,K](bf16) @ Bt[N,K]^T(bf16), f32 accum.
// 128x128 tile, 4 waves (2x2), each wave 64x64 = 4x4 frags of 16x16x32 MFMA.
// Epilogue fuses attention dots (from f32 accumulators) with 16-lane reduce
// + atomics, and stores bf16 C.
// Fragment maps (guide §3, HW-verified): A: row=lane&15, k=(lane>>4)*8+j;
// B: col=lane&15, same k; D: col=lane&15, row=(lane>>4)*4+reg.
// ---------------------------------------------------------------------------
template <int HEADS>
__global__ __launch_bounds__(256) void gemm_mfma(const unsigned short* __restrict__ A,
                                                 const unsigned short* __restrict__ Bt,
                                                 unsigned short* __restrict__ Cb,
                                                 const float* __restrict__ att_src,
                                                 const float* __restrict__ att_dst,
                                                 float* __restrict__ asrc,
                                                 float* __restrict__ adst,
                                                 int M, int N, int K)
{
    const int BM = 128, BK = 32, LDT = 40;       // LDS row stride: 32 + 8 pad (16B-aligned)
    __shared__ unsigned short As[BM * LDT];
    __shared__ unsigned short Bs[BM * LDT];
    int tid = threadIdx.x, lane = tid & 63, wid = tid >> 6;
    int wm = wid >> 1, wn = wid & 1;
    int row0 = blockIdx.x * BM, col0 = blockIdx.y * 128;
    f32x4 acc[4][4] = {};

    for (int k0 = 0; k0 < K; k0 += BK) {
        #pragma unroll
        for (int i = 0; i < 2; i++) {            // 512 chunks of 16B per tile
            int id = tid + i * 256;
            int r = id >> 2, c8 = (id & 3) * 8;
            int4 va = make_int4(0, 0, 0, 0);
            if (row0 + r < M)
                va = *(const int4*)&A[(size_t)(row0 + r) * K + k0 + c8];
            *(int4*)&As[r * LDT + c8] = va;
            int4 vb = *(const int4*)&Bt[(size_t)(col0 + r) * K + k0 + c8];
            *(int4*)&Bs[r * LDT + c8] = vb;
        }
        __syncthreads();
        bf16x8 a[4], b[4];
        #pragma unroll
        for (int mr = 0; mr < 4; mr++)
            a[mr] = *(const bf16x8*)&As[(wm * 64 + mr * 16 + (lane & 15)) * LDT + (lane >> 4) * 8];
        #pragma unroll
        for (int nr = 0; nr < 4; nr++)
            b[nr] = *(const bf16x8*)&Bs[(wn * 64 + nr * 16 + (lane & 15)) * LDT + (lane >> 4) * 8];
        #pragma unroll
        for (int mr = 0; mr < 4; mr++)
            #pragma unroll
            for (int nr = 0; nr < 4; nr++)
                acc[mr][nr] = __builtin_amdgcn_mfma_f32_16x16x32_bf16(a[mr], b[nr], acc[mr][nr], 0, 0, 0);
        __syncthreads();
    }

    // epilogue: bf16 C store + fused attention dots from f32 accumulators
    int colbase = col0 + wn * 64;
    int head = colbase >> 7;                     // 64-col wave span stays in one head
    float vs[4], vd[4];
    #pragma unroll
    for (int nr = 0; nr < 4; nr++) {
        vs[nr] = att_src[colbase + nr * 16 + (lane & 15)];
        vd[nr] = att_dst[colbase + nr * 16 + (lane & 15)];
    }
    #pragma unroll
    for (int mr = 0; mr < 4; mr++) {
        #pragma unroll
        for (int r = 0; r < 4; r++) {
            int row = row0 + wm * 64 + mr * 16 + (lane >> 4) * 4 + r;
            if (row < M) {                       // uniform across the 16-lane reduce group
                float ps = 0.f, pd = 0.f;
                #pragma unroll
                for (int nr = 0; nr < 4; nr++) {
                    ps += acc[mr][nr][r] * vs[nr];
                    pd += acc[mr][nr][r] * vd[nr];
                }
                #pragma unroll
                for (int off = 8; off > 0; off >>= 1) {
                    ps += __shfl_xor(ps, off);
                    pd += __shfl_xor(pd, off);
                }
                if ((lane & 15) == 0) {
                    atomicAdd(&asrc[row * HEADS + head], ps);
                    atomicAdd(&adst[row * HEADS + head], pd);
                }
                #pragma unroll
                for (int nr = 0; nr < 4; nr++)
                    Cb[(size_t)row * N + colbase + nr * 16 + (lane & 15)] = f2b(acc[mr][nr][r]);
            }
        }
    }
}

// ---------------------------------------------------------------------------
// GAT aggregation: per dst node -> softmax over in-edges -> weighted gather sum.
// Softmax logits fully f32; messages gathered from the bf16 h-table.
// HEADS==2 writes bf16 output (feeds layer-2 GEMM A); HEADS==1 writes f32.
// ---------------------------------------------------------------------------
template <int HEADS>
__global__ __launch_bounds__(256) void gat_aggregate(const unsigned short* __restrict__ hb,
                                                     const float* __restrict__ asrc,
                                                     const float* __restrict__ adst,
                                                     const int* __restrict__ rowptr,
                                                     const int* __restrict__ csr_src,
                                                     const float* __restrict__ bias,
                                                     unsigned short* __restrict__ outb,
                                                     float* __restrict__ outf, int n)
{
    const int CH   = HEADS * 128;
    const int PER  = CH / 64;          // channels per lane
    const int MAXE = 128;              // LDS-cached edge budget per node
    __shared__ float w_lds[4][MAXE * HEADS];
    __shared__ int   s_lds[4][MAXE];
    int wid = threadIdx.x >> 6, lane = threadIdx.x & 63;
    int node = blockIdx.x * 4 + wid;
    if (node >= n) return;

    int start = rowptr[node], end = rowptr[node + 1];
    int deg = end - start;
    bool fast = (deg <= MAXE);
    int head = (PER == 4) ? (lane >> 5) : 0;

    float ad[HEADS], m[HEADS], dsum[HEADS];
    #pragma unroll
    for (int hh = 0; hh < HEADS; hh++) { ad[hh] = adst[node * HEADS + hh]; m[hh] = -1e30f; dsum[hh] = 0.f; }

    // pass 1: e = leaky_relu(asrc[src]+adst[dst]); cache in LDS; wave max
    for (int base = 0; base < deg; base += 64) {
        int j = base + lane;
        if (j < deg) {
            int s = csr_src[start + j];
            if (fast) s_lds[wid][j] = s;
            #pragma unroll
            for (int hh = 0; hh < HEADS; hh++) {
                float v = asrc[s * HEADS + hh] + ad[hh];
                v = (v > 0.f) ? v : 0.2f * v;
                if (fast) w_lds[wid][j * HEADS + hh] = v;
                m[hh] = fmaxf(m[hh], v);
            }
        }
    }
    #pragma unroll
    for (int hh = 0; hh < HEADS; hh++)
        #pragma unroll
        for (int off = 32; off > 0; off >>= 1)
            m[hh] = fmaxf(m[hh], __shfl_xor(m[hh], off));

    // pass 2: exp(e - m), cache, wave sum
    for (int base = 0; base < deg; base += 64) {
        int j = base + lane;
        if (j < deg) {
            #pragma unroll
            for (int hh = 0; hh < HEADS; hh++) {
                float v;
                if (fast) v = w_lds[wid][j * HEADS + hh];
                else {
                    int s = csr_src[start + j];
                    v = asrc[s * HEADS + hh] + ad[hh];
                    v = (v > 0.f) ? v : 0.2f * v;
                }
                float ex = __expf(v - m[hh]);
                if (fast) w_lds[wid][j * HEADS + hh] = ex;
                dsum[hh] += ex;
            }
        }
    }
    #pragma unroll
    for (int hh = 0; hh < HEADS; hh++)
        #pragma unroll
        for (int off = 32; off > 0; off >>= 1)
            dsum[hh] += __shfl_xor(dsum[hh], off);

    float m_l    = (HEADS == 2 && head) ? m[HEADS - 1] : m[0];
    float ad_l   = (HEADS == 2 && head) ? ad[HEADS - 1] : ad[0];
    float inv_l  = 1.0f / ((HEADS == 2 && head) ? dsum[HEADS - 1] : dsum[0]);

    // pass 3: weighted gather-accumulate from bf16 table
    float acc[PER];
    #pragma unroll
    for (int p = 0; p < PER; p++) acc[p] = 0.f;

    auto edge_sw = [&](int j, int& s, float& wgt) {
        if (fast) {
            s   = s_lds[wid][j];
            wgt = w_lds[wid][j * HEADS + head] * inv_l;
        } else {
            s = csr_src[start + j];
            float v = asrc[s * HEADS + head] + ad_l;
            v = (v > 0.f) ? v : 0.2f * v;
            wgt = __expf(v - m_l) * inv_l;
        }
    };

    const int U = 8;
    int j = 0;
    for (; j + U <= deg; j += U) {
        int su[U]; float wu[U];
        #pragma unroll
        for (int u = 0; u < U; u++) edge_sw(j + u, su[u], wu[u]);
        if (PER == 4) {
            ushort4 hv[U];
            #pragma unroll
            for (int u = 0; u < U; u++)
                hv[u] = *(const ushort4*)&hb[(size_t)su[u] * CH + lane * 4];
            #pragma unroll
            for (int u = 0; u < U; u++) {
                acc[0] += wu[u] * b2f(hv[u].x); acc[1] += wu[u] * b2f(hv[u].y);
                acc[2] += wu[u] * b2f(hv[u].z); acc[3] += wu[u] * b2f(hv[u].w);
            }
        } else {
            ushort2 hv[U];
            #pragma unroll
            for (int u = 0; u < U; u++)
                hv[u] = *(const ushort2*)&hb[(size_t)su[u] * CH + lane * 2];
            #pragma unroll
            for (int u = 0; u < U; u++) {
                acc[0] += wu[u] * b2f(hv[u].x); acc[1] += wu[u] * b2f(hv[u].y);
            }
        }
    }
    for (; j < deg; j++) {
        int s; float wgt;
        edge_sw(j, s, wgt);
        if (PER == 4) {
            ushort4 hv = *(const ushort4*)&hb[(size_t)s * CH + lane * 4];
            acc[0] += wgt * b2f(hv.x); acc[1] += wgt * b2f(hv.y);
            acc[2] += wgt * b2f(hv.z); acc[3] += wgt * b2f(hv.w);
        } else {
            ushort2 hv = *(const ushort2*)&hb[(size_t)s * CH + lane * 2];
            acc[0] += wgt * b2f(hv.x); acc[1] += wgt * b2f(hv.y);
        }
    }

    if (HEADS == 2) {                    // bf16 out (feeds layer-2 MFMA GEMM)
        ushort4 ov;
        ov.x = f2b(fmaxf(acc[0] + bias[lane * 4 + 0], 0.f));
        ov.y = f2b(fmaxf(acc[1] + bias[lane * 4 + 1], 0.f));
        ov.z = f2b(fmaxf(acc[2] + bias[lane * 4 + 2], 0.f));
        ov.w = f2b(fmaxf(acc[3] + bias[lane * 4 + 3], 0.f));
        *(ushort4*)&outb[(size_t)node * 256 + lane * 4] = ov;
    } else {                             // f32 out (feeds pool)
        float2 ov;
        ov.x = fmaxf(acc[0] + bias[lane * 2 + 0], 0.f);
        ov.y = fmaxf(acc[1] + bias[lane * 2 + 1], 0.f);
        *(float2*)&outf[(size_t)node * 128 + lane * 2] = ov;
    }
}

// ---------------------------------------------------------------------------
// Sorted-batch pooling (inline bounds search) + MLP head
// ---------------------------------------------------------------------------
__global__ __launch_bounds__(256) void pool_seg(const float* __restrict__ h,
                                                const int* __restrict__ batch,
                                                float* __restrict__ pooled)
{
    __shared__ float2 part[4][64];
    int g = blockIdx.x;
    int lo = 0, hi = NN;
    while (lo < hi) { int mid = (lo + hi) >> 1; if (batch[mid] < g) lo = mid + 1; else hi = mid; }
    int start = lo;
    lo = 0; hi = NN;
    while (lo < hi) { int mid = (lo + hi) >> 1; if (batch[mid] < g + 1) lo = mid + 1; else hi = mid; }
    int end = lo;
    int lane = threadIdx.x & 63, w = threadIdx.x >> 6;
    float2 acc = make_float2(0.f, 0.f);
    for (int i = start + w; i < end; i += 4) {
        float2 v = *(const float2*)&h[(size_t)i * 128 + lane * 2];
        acc.x += v.x; acc.y += v.y;
    }
    part[w][lane] = acc;
    __syncthreads();
    if (w == 0) {
        float2 s = part[0][lane];
        s.x += part[1][lane].x + part[2][lane].x + part[3][lane].x;
        s.y += part[1][lane].y + part[2][lane].y + part[3][lane].y;
        float invc = 1.0f / fmaxf((float)(end - start), 1.0f);
        pooled[g * 128 + lane * 2 + 0] = s.x * invc;
        pooled[g * 128 + lane * 2 + 1] = s.y * invc;
    }
}

__global__ __launch_bounds__(64) void head_mlp(const float* __restrict__ pooled,
                                               const float* __restrict__ lw1,
                                               const float* __restrict__ lb1,
                                               const float* __restrict__ lw2,
                                               const float* __restrict__ lb2,
                                               float* __restrict__ out)
{
    int g = blockIdx.x, lane = threadIdx.x;
    __shared__ float p[128];
    p[lane]      = pooled[g * 128 + lane];
    p[lane + 64] = pooled[g * 128 + lane + 64];
    __syncthreads();
    float z = lb1[lane];
    #pragma unroll 8
    for (int k = 0; k < 128; k++) z += p[k] * lw1[k * 64 + lane];
    z = fmaxf(z, 0.f);
    float v = z * lw2[lane];
    #pragma unroll
    for (int off = 32; off > 0; off >>= 1) v += __shfl_xor(v, off);
    if (lane == 0) out[g] = v + lb2[0];
}

// ---------------------------------------------------------------------------
extern "C" void kernel_launch(void* const* d_in, const int* in_sizes, int n_in,
                              void* d_out, int out_size, void* d_ws, size_t ws_size,
                              hipStream_t stream)
{
    const float* x      = (const float*)d_in[0];
    const int*   ei_raw = (const int*)d_in[1];
    const int*   bat_raw= (const int*)d_in[2];
    const float* W1   = (const float*)d_in[4];
    const float* as1  = (const float*)d_in[5];
    const float* ad1  = (const float*)d_in[6];
    const float* b1   = (const float*)d_in[7];
    const float* W2   = (const float*)d_in[8];
    const float* as2  = (const float*)d_in[9];
    const float* ad2  = (const float*)d_in[10];
    const float* b2   = (const float*)d_in[11];
    const float* lw1  = (const float*)d_in[12];
    const float* lb1  = (const float*)d_in[13];
    const float* lw2  = (const float*)d_in[14];
    const float* lb2  = (const float*)d_in[15];
    float* out = (float*)d_out;

    char* w = (char*)d_ws;
    auto alloc = [&](size_t bytes) { char* p = w; w += (bytes + 255) & ~size_t(255); return p; };
    unsigned short* xb    = (unsigned short*)alloc((size_t)NN * 128 * 2);
    unsigned short* w1t   = (unsigned short*)alloc((size_t)256 * 128 * 2);
    unsigned short* w2t   = (unsigned short*)alloc((size_t)128 * 256 * 2);
    unsigned short* h1b   = (unsigned short*)alloc((size_t)NN * 256 * 2);
    unsigned short* h2b   = (unsigned short*)alloc((size_t)NN * 128 * 2);
    unsigned short* o1b   = (unsigned short*)alloc((size_t)NN * 256 * 2);
    float*          o2    = (float*)alloc((size_t)NN * 128 * 4);
    // alpha block: asrc1[NN*2], adst1[NN*2], asrc2[NN], adst2[NN] — one memset
    float* alph  = (float*)alloc((size_t)NN * 6 * 4);
    float* asrc1 = alph;
    float* adst1 = alph + (size_t)NN * 2;
    float* asrc2 = alph + (size_t)NN * 4;
    float* adst2 = alph + (size_t)NN * 5;
    int*   cnts  = (int*)alloc((size_t)NN * 4);
    int*   rowp  = (int*)alloc((size_t)(NN + 4) * 4);
    int*   curs  = (int*)alloc((size_t)NN * 4);
    int*   csr   = (int*)alloc((size_t)NEP * 4);
    float* pooled= (float*)alloc((size_t)NG * 128 * 4);
    int*   bat32 = (int*)alloc((size_t)NN * 4);
    int*   flags = (int*)alloc(2 * 4);

    // normalize integer inputs
    detect_i64<<<1, 256, 0, stream>>>(ei_raw, 2 * NE, &flags[0]);
    detect_i64<<<1, 256, 0, stream>>>(bat_raw, NN, &flags[1]);
    cvt_idx<<<(NN + 255) / 256, 256, 0, stream>>>(bat_raw, &flags[1], bat32, NN);

    // CSR build (reads raw edges directly)
    hipMemsetAsync(cnts, 0, NN * 4, stream);
    hipMemsetAsync(alph, 0, (size_t)NN * 6 * 4, stream);
    edge_hist<<<(NEP + 255) / 256, 256, 0, stream>>>(ei_raw, &flags[0], cnts);
    scan_counts<<<1, 1024, 0, stream>>>(cnts, rowp, curs, NN);
    edge_scatter<<<(NEP + 255) / 256, 256, 0, stream>>>(ei_raw, &flags[0], curs, csr);

    // bf16 pre-casts
    cast_bf16_vec<<<(NN * 128 / 4 + 255) / 256, 256, 0, stream>>>(x, xb, NN * 128 / 4);
    cast_transpose<<<(256 * 128 + 255) / 256, 256, 0, stream>>>(W1, w1t, 128, 256);
    cast_transpose<<<(128 * 256 + 255) / 256, 256, 0, stream>>>(W2, w2t, 256, 128);

    // layer 1: MFMA GEMM (bf16 h + fused alpha dots) ; aggregate -> bf16 o1
    gemm_mfma<2><<<dim3((NN + 127) / 128, 2), 256, 0, stream>>>(
        xb, w1t, h1b, as1, ad1, asrc1, adst1, NN, 256, 128);
    gat_aggregate<2><<<(NN + 3) / 4, 256, 0, stream>>>(h1b, asrc1, adst1, rowp, csr, b1,
                                                       o1b, nullptr, NN);

    // layer 2
    gemm_mfma<1><<<dim3((NN + 127) / 128, 1), 256, 0, stream>>>(
        o1b, w2t, h2b, as2, ad2, asrc2, adst2, NN, 128, 256);
    gat_aggregate<1><<<(NN + 3) / 4, 256, 0, stream>>>(h2b, asrc2, adst2, rowp, csr, b2,
                                                       nullptr, o2, NN);

    // pool (sorted batch, inline bounds) + head
    pool_seg<<<NG, 256, 0, stream>>>(o2, bat32, pooled);
    head_mlp<<<NG, 64, 0, stream>>>(pooled, lw1, lb1, lw2, lb2, out);
}